// Round 1
// baseline (377.560 us; speedup 1.0000x reference)
//
#include <hip/hip_runtime.h>

#define TOT 288

// ---------------- workspace layout (float offsets) ----------------
// tw     :        0  (256)            e^{-2pi i k/128}, k=0..127, float2
// alpha  :      256  (131072)         [b][i][f][g] float2
// invd1  :   131328  (524288)         [i][o][f][p] float2
// invd2  :   655616  (524288)         [i][o][g][q] float2
// s1     :  1179904  (524288)         [i][o][f][g] float2
// or1    :  1704192  (131072)         [b][o][f][g] float2
// or2    :  1835264  (131072)         [b][o][p][q] float2
// e1     :  1966336  (4194304)        [i][o][p][z] float2
// e2     :  6160640  (4194304)        [i][o][q][x] float2
// total  : 10354944 floats = 41.4 MB

__global__ void k_tw(float2* __restrict__ tw) {
    int k = threadIdx.x;
    float th = 0.049087385212340517f * (float)k;  // 2*pi/128 * k
    float s, c;
    sincosf(th, &s, &c);
    tw[k] = make_float2(c, -s);                   // e^{-i th}
}

__global__ void k_invd(const float* __restrict__ wr, const float* __restrict__ wi,
                       float2* __restrict__ invd1, float2* __restrict__ invd2) {
    int idx = blockIdx.x * 256 + threadIdx.x;     // [io][f][p], 262144 total
    int p  = idx & 15;
    int f  = (idx >> 4) & 15;
    int io = idx >> 8;
    const float W1 = 6.2340979026f;               // 2*pi*127/128
    {
        float pr = wr[io * TOT + p], pim = wi[io * TOT + p];
        float dr = -pr, di = W1 * (float)f - pim;
        float s = 1.0f / (dr * dr + di * di);
        invd1[idx] = make_float2(dr * s, -di * s);
    }
    {
        float pr = wr[io * TOT + 16 + p], pim = wi[io * TOT + 16 + p];
        float dr = -pr, di = W1 * (float)f - pim;
        float s = 1.0f / (dr * dr + di * di);
        invd2[idx] = make_float2(dr * s, -di * s);
    }
}

__global__ void k_e(const float* __restrict__ wr, const float* __restrict__ wi,
                    float2* __restrict__ e1, float2* __restrict__ e2) {
    int idx = blockIdx.x * 256 + threadIdx.x;     // [io][p][z], 2097152 total
    int z  = idx & 127;
    int p  = (idx >> 7) & 15;
    int io = idx >> 11;
    float t = (float)z * 0.007874015748031496f;   // z/127
    {
        float pr = wr[io * TOT + p], pim = wi[io * TOT + p];
        float m = expf(pr * t);
        float s, c;
        sincosf(pim * t, &s, &c);
        e1[idx] = make_float2(m * c, m * s);
    }
    {
        float pr = wr[io * TOT + 16 + p], pim = wi[io * TOT + 16 + p];
        float m = expf(pr * t);
        float s, c;
        sincosf(pim * t, &s, &c);
        e2[idx] = make_float2(m * c, m * s);
    }
}

// alpha[b,i,f,g] = sum_{y,x} X[y,x] e^{-2pi i f y/128} e^{-2pi i g x/128}
__global__ __launch_bounds__(256) void k_alpha(const float* __restrict__ x,
                                               const float2* __restrict__ tw,
                                               float2* __restrict__ alpha) {
    __shared__ float twr[128], twi[128];
    __shared__ float T1r[16][128], T1i[16][128];
    int t = threadIdx.x;
    int bi = blockIdx.x;
    if (t < 128) { float2 v = tw[t]; twr[t] = v.x; twi[t] = v.y; }
    __syncthreads();

    const float* xp = x + (size_t)bi * 16384;
    int xcol = t & 127;
    int f0 = (t >> 7) * 8;
    float ar[8], ai[8];
    int kk[8];
#pragma unroll
    for (int j = 0; j < 8; ++j) { ar[j] = 0.f; ai[j] = 0.f; kk[j] = 0; }
    for (int y = 0; y < 128; ++y) {
        float xv = xp[y * 128 + xcol];
#pragma unroll
        for (int j = 0; j < 8; ++j) {
            ar[j] += twr[kk[j]] * xv;
            ai[j] += twi[kk[j]] * xv;
            kk[j] = (kk[j] + f0 + j) & 127;
        }
    }
#pragma unroll
    for (int j = 0; j < 8; ++j) { T1r[f0 + j][xcol] = ar[j]; T1i[f0 + j][xcol] = ai[j]; }
    __syncthreads();

    int g = t & 15, f = t >> 4;
    float sr = 0.f, si = 0.f;
    int kg = 0;
    for (int xx = 0; xx < 128; ++xx) {
        float trv = T1r[f][xx], tiv = T1i[f][xx];
        float cr = twr[kg], ci = twi[kg];
        sr += trv * cr - tiv * ci;
        si += trv * ci + tiv * cr;
        kg = (kg + g) & 127;
    }
    alpha[bi * 256 + t] = make_float2(sr, si);
}

// s1[i,o,f,g] = sum_q invd2[g,q] * ( sum_p res[p,q] * invd1[f,p] )
__global__ __launch_bounds__(256) void k_s1(const float* __restrict__ wr, const float* __restrict__ wi,
                                            const float2* __restrict__ invd1,
                                            const float2* __restrict__ invd2,
                                            float2* __restrict__ s1) {
    int io = blockIdx.x;
    int t = threadIdx.x;
    __shared__ float D1r[16][16], D1i[16][16];   // [f][p]
    __shared__ float D2r[16][16], D2i[16][16];   // [g][q]
    __shared__ float Rr[16][16], Ri[16][16];     // [p][q]
    __shared__ float R1r[16][16], R1i[16][16];   // [f][q]
    {
        float2 v1 = invd1[io * 256 + t]; D1r[t >> 4][t & 15] = v1.x; D1i[t >> 4][t & 15] = v1.y;
        float2 v2 = invd2[io * 256 + t]; D2r[t >> 4][t & 15] = v2.x; D2i[t >> 4][t & 15] = v2.y;
        Rr[t >> 4][t & 15] = wr[io * TOT + 32 + t];
        Ri[t >> 4][t & 15] = wi[io * TOT + 32 + t];
    }
    __syncthreads();
    int f = t >> 4, q = t & 15;
    float sr = 0.f, si = 0.f;
#pragma unroll
    for (int p = 0; p < 16; ++p) {
        float rr = Rr[p][q], ri = Ri[p][q];
        float dr = D1r[f][p], di = D1i[f][p];
        sr += rr * dr - ri * di;
        si += rr * di + ri * dr;
    }
    R1r[f][q] = sr; R1i[f][q] = si;
    __syncthreads();
    int g = t & 15;
    sr = 0.f; si = 0.f;
#pragma unroll
    for (int qq = 0; qq < 16; ++qq) {
        float rr = R1r[f][qq], ri = R1i[f][qq];
        float dr = D2r[g][qq], di = D2i[g][qq];
        sr += rr * dr - ri * di;
        si += rr * di + ri * dr;
    }
    s1[io * 256 + f * 16 + g] = make_float2(sr, si);
}

// or1[b,o,f,g] = sum_i alpha[b,i,f,g] * s1[i,o,f,g]
__global__ __launch_bounds__(256) void k_or1(const float2* __restrict__ alpha,
                                             const float2* __restrict__ s1,
                                             float2* __restrict__ or1) {
    int b = blockIdx.x >> 5, o = blockIdx.x & 31;
    int t = threadIdx.x;
    float sr = 0.f, si = 0.f;
    for (int i = 0; i < 32; ++i) {
        float2 a = alpha[(b * 32 + i) * 256 + t];
        float2 s = s1[(i * 32 + o) * 256 + t];
        sr += a.x * s.x - a.y * s.y;
        si += a.x * s.y + a.y * s.x;
    }
    or1[blockIdx.x * 256 + t] = make_float2(sr, si);
}

// or2[b,o,p,q] = sum_i res_i[p,q] * sum_g invd2_i[g,q] * sum_f alpha_i[f,g]*invd1_i[f,p]
__global__ __launch_bounds__(256) void k_or2(const float* __restrict__ wr, const float* __restrict__ wi,
                                             const float2* __restrict__ alpha,
                                             const float2* __restrict__ invd1,
                                             const float2* __restrict__ invd2,
                                             float2* __restrict__ or2) {
    int b = blockIdx.x >> 5, o = blockIdx.x & 31;
    int t = threadIdx.x;
    __shared__ float Ar[16][16], Ai[16][16];     // [f][g]
    __shared__ float D1r[16][16], D1i[16][16];   // [f][p]
    __shared__ float D2r[16][16], D2i[16][16];   // [g][q]
    __shared__ float Rr[16][16], Ri[16][16];     // [p][q]
    __shared__ float Vr[16][16], Vi[16][16];     // [p][g]
    int p_ = t >> 4, q_ = t & 15;
    float accr = 0.f, acci = 0.f;
    for (int i = 0; i < 32; ++i) {
        int io = i * 32 + o;
        float2 a  = alpha[(b * 32 + i) * 256 + t];
        float2 d1 = invd1[io * 256 + t];
        float2 d2 = invd2[io * 256 + t];
        float rr = wr[io * TOT + 32 + t];
        float ri = wi[io * TOT + 32 + t];
        __syncthreads();   // previous iteration's readers done
        Ar[p_][q_] = a.x;  Ai[p_][q_] = a.y;
        D1r[p_][q_] = d1.x; D1i[p_][q_] = d1.y;
        D2r[p_][q_] = d2.x; D2i[p_][q_] = d2.y;
        Rr[p_][q_] = rr;   Ri[p_][q_] = ri;
        __syncthreads();
        // V[p][g] = sum_f A[f][g] * D1[f][p]   (thread: p=p_, g=q_)
        float vr = 0.f, vi = 0.f;
#pragma unroll
        for (int f = 0; f < 16; ++f) {
            float ar2 = Ar[f][q_], ai2 = Ai[f][q_];
            float dr = D1r[f][p_], di = D1i[f][p_];
            vr += ar2 * dr - ai2 * di;
            vi += ar2 * di + ai2 * dr;
        }
        Vr[p_][q_] = vr; Vi[p_][q_] = vi;
        __syncthreads();
        // T[p][q] = sum_g V[p][g]*D2[g][q];  acc += R[p][q]*T
        float tr = 0.f, ti = 0.f;
#pragma unroll
        for (int g = 0; g < 16; ++g) {
            float vr2 = Vr[p_][g], vi2 = Vi[p_][g];
            float dr = D2r[g][q_], di = D2i[g][q_];
            tr += vr2 * dr - vi2 * di;
            ti += vr2 * di + vi2 * dr;
        }
        float rr2 = Rr[p_][q_], ri2 = Ri[p_][q_];
        accr += rr2 * tr - ri2 * ti;
        acci += rr2 * ti + ri2 * tr;
    }
    or2[blockIdx.x * 256 + t] = make_float2(accr, acci);
}

// out[b,o,z,x] = (1/16384) * Re[ sum_{f,g} or1[f,g] E^{fz}E^{gx}
//                              + sum_i (e1_i^T @ or2 @ e2_i)[z,x] ]
__global__ __launch_bounds__(512) void k_x12(const float2* __restrict__ or1,
                                             const float2* __restrict__ or2,
                                             const float2* __restrict__ e1t,
                                             const float2* __restrict__ e2t,
                                             const float2* __restrict__ tw,
                                             float* __restrict__ out) {
    int bo = blockIdx.x;
    int o = bo & 31;
    int t = threadIdx.x;
    __shared__ float E1r[16][128], E1i[16][128];
    __shared__ float E2r[16][128], E2i[16][128];
    __shared__ float Gr[128][17], Gi[128][17];
    __shared__ float M1r[16][16], M1i[16][16];
    __shared__ float M2r[16][16], M2i[16][16];
    __shared__ float twr[128], twi[128];

    if (t < 128) { float2 v = tw[t]; twr[t] = v.x; twi[t] = v.y; }
    if (t < 256) {
        float2 v1 = or1[bo * 256 + t];
        M1r[t >> 4][t & 15] = v1.x; M1i[t >> 4][t & 15] = v1.y;
        float2 v2 = or2[bo * 256 + t];
        M2r[t >> 4][t & 15] = v2.x; M2i[t >> 4][t & 15] = v2.y;
    }

    int zg = t >> 4;        // 0..31
    int xg = t & 15;        // 0..15
    int z0 = zg * 4, x0 = xg * 8;
    float acc[4][8];
#pragma unroll
    for (int k = 0; k < 4; ++k)
#pragma unroll
        for (int j = 0; j < 8; ++j) acc[k][j] = 0.f;

    __syncthreads();
    // phase 1: Fourier basis, E = e^{+2pi i k/128} = conj(tw)
    for (int idx = t; idx < 2048; idx += 512) {
        int f = idx >> 7, z = idx & 127;
        int k = (f * z) & 127;
        float cr = twr[k], ci = -twi[k];
        E1r[f][z] = cr; E1i[f][z] = ci;
        E2r[f][z] = cr; E2i[f][z] = ci;
    }
    __syncthreads();
    // G[z][q] = sum_f E1[f][z] * M1[f][q]   (thread: 4 z, q=xg)
#pragma unroll
    for (int k = 0; k < 4; ++k) {
        int z = z0 + k;
        float gr = 0.f, gi = 0.f;
#pragma unroll
        for (int f = 0; f < 16; ++f) {
            float er = E1r[f][z], ei = E1i[f][z];
            float mr = M1r[f][xg], mi = M1i[f][xg];
            gr += er * mr - ei * mi;
            gi += er * mi + ei * mr;
        }
        Gr[z][xg] = gr; Gi[z][xg] = gi;
    }
    __syncthreads();
    // acc += Re(G[z][q] * E2[q][x])
#pragma unroll 4
    for (int q = 0; q < 16; ++q) {
        float g0r = Gr[z0][q],     g0i = Gi[z0][q];
        float g1r = Gr[z0 + 1][q], g1i = Gi[z0 + 1][q];
        float g2r = Gr[z0 + 2][q], g2i = Gi[z0 + 2][q];
        float g3r = Gr[z0 + 3][q], g3i = Gi[z0 + 3][q];
#pragma unroll
        for (int j = 0; j < 8; ++j) {
            float er = E2r[q][x0 + j], ei = E2i[q][x0 + j];
            acc[0][j] += g0r * er - g0i * ei;
            acc[1][j] += g1r * er - g1i * ei;
            acc[2][j] += g2r * er - g2i * ei;
            acc[3][j] += g3r * er - g3i * ei;
        }
    }

    // phase 2: 32 Laplace modes
    for (int i = 0; i < 32; ++i) {
        __syncthreads();          // E/G consumers of previous iteration done
        const float2* p1 = e1t + (size_t)(i * 32 + o) * 2048;
        const float2* p2 = e2t + (size_t)(i * 32 + o) * 2048;
        for (int idx = t; idx < 2048; idx += 512) {
            float2 v = p1[idx];
            E1r[idx >> 7][idx & 127] = v.x; E1i[idx >> 7][idx & 127] = v.y;
            float2 w = p2[idx];
            E2r[idx >> 7][idx & 127] = w.x; E2i[idx >> 7][idx & 127] = w.y;
        }
        __syncthreads();
#pragma unroll
        for (int k = 0; k < 4; ++k) {
            int z = z0 + k;
            float gr = 0.f, gi = 0.f;
#pragma unroll
            for (int f = 0; f < 16; ++f) {
                float er = E1r[f][z], ei = E1i[f][z];
                float mr = M2r[f][xg], mi = M2i[f][xg];
                gr += er * mr - ei * mi;
                gi += er * mi + ei * mr;
            }
            Gr[z][xg] = gr; Gi[z][xg] = gi;
        }
        __syncthreads();
#pragma unroll 4
        for (int q = 0; q < 16; ++q) {
            float g0r = Gr[z0][q],     g0i = Gi[z0][q];
            float g1r = Gr[z0 + 1][q], g1i = Gi[z0 + 1][q];
            float g2r = Gr[z0 + 2][q], g2i = Gi[z0 + 2][q];
            float g3r = Gr[z0 + 3][q], g3i = Gi[z0 + 3][q];
#pragma unroll
            for (int j = 0; j < 8; ++j) {
                float er = E2r[q][x0 + j], ei = E2i[q][x0 + j];
                acc[0][j] += g0r * er - g0i * ei;
                acc[1][j] += g1r * er - g1i * ei;
                acc[2][j] += g2r * er - g2i * ei;
                acc[3][j] += g3r * er - g3i * ei;
            }
        }
    }

    const float sc = 1.0f / 16384.0f;
    float* po = out + (size_t)bo * 16384 + z0 * 128 + x0;
#pragma unroll
    for (int k = 0; k < 4; ++k) {
        float4 a = make_float4(acc[k][0] * sc, acc[k][1] * sc, acc[k][2] * sc, acc[k][3] * sc);
        float4 b = make_float4(acc[k][4] * sc, acc[k][5] * sc, acc[k][6] * sc, acc[k][7] * sc);
        *(float4*)(po + k * 128) = a;
        *(float4*)(po + k * 128 + 4) = b;
    }
}

extern "C" void kernel_launch(void* const* d_in, const int* in_sizes, int n_in,
                              void* d_out, int out_size, void* d_ws, size_t ws_size,
                              hipStream_t stream) {
    const float* x  = (const float*)d_in[0];
    const float* wr = (const float*)d_in[1];
    const float* wi = (const float*)d_in[2];
    float* out = (float*)d_out;
    float* ws = (float*)d_ws;

    float2* tw    = (float2*)(ws + 0);
    float2* alpha = (float2*)(ws + 256);
    float2* invd1 = (float2*)(ws + 131328);
    float2* invd2 = (float2*)(ws + 655616);
    float2* s1    = (float2*)(ws + 1179904);
    float2* or1   = (float2*)(ws + 1704192);
    float2* or2   = (float2*)(ws + 1835264);
    float2* e1    = (float2*)(ws + 1966336);
    float2* e2    = (float2*)(ws + 6160640);

    hipLaunchKernelGGL(k_tw,    dim3(1),    dim3(128), 0, stream, tw);
    hipLaunchKernelGGL(k_invd,  dim3(1024), dim3(256), 0, stream, wr, wi, invd1, invd2);
    hipLaunchKernelGGL(k_e,     dim3(8192), dim3(256), 0, stream, wr, wi, e1, e2);
    hipLaunchKernelGGL(k_alpha, dim3(256),  dim3(256), 0, stream, x, tw, alpha);
    hipLaunchKernelGGL(k_s1,    dim3(1024), dim3(256), 0, stream, wr, wi, invd1, invd2, s1);
    hipLaunchKernelGGL(k_or1,   dim3(256),  dim3(256), 0, stream, alpha, s1, or1);
    hipLaunchKernelGGL(k_or2,   dim3(256),  dim3(256), 0, stream, wr, wi, alpha, invd1, invd2, or2);
    hipLaunchKernelGGL(k_x12,   dim3(256),  dim3(512), 0, stream, or1, or2, e1, e2, tw, out);
}

// Round 2
// 130.628 us; speedup vs baseline: 2.8903x; 2.8903x over previous
//
#include <hip/hip_runtime.h>

#define TOT 288

typedef short short8 __attribute__((ext_vector_type(8)));
typedef float f32x4 __attribute__((ext_vector_type(4)));
typedef unsigned short u16;
typedef u16 u16x8 __attribute__((ext_vector_type(8)));

__device__ __forceinline__ u16 f2bf(float f) {
    unsigned u = __builtin_bit_cast(unsigned, f);
    u += 0x7fffu + ((u >> 16) & 1u);
    return (u16)(u >> 16);
}

// ---------------- workspace layout (float offsets) ----------------
// tw     :        0  (256)
// alpha  :      256  (131072)       [b][i][f][g] float2
// invd1  :   131328  (524288)       [i][o][f][p] float2
// invd2  :   655616  (524288)       [i][o][g][q] float2
// s1     :  1179904  (524288)       [i][o][f][g] float2
// or1    :  1704192  (131072)       [b][o][f][g] float2
// or2    :  1835264  (131072)       [b][o][p][q] float2
// e1A    :  1966336  (2097152)      bf16 [io][128z][32k] swizzled (A-frag layout)
// e2B    :  4063488  (2097152)      bf16 [io][128x][32k] swizzled (B-frag layout, k>=16 negated imag)
// fA     :  6160640  (2048)         bf16 Fourier A table [128z][32k]
// fB     :  6162688  (2048)         bf16 Fourier B table [128x][32k]

__global__ void k_tw(float2* __restrict__ tw) {
    int k = threadIdx.x;
    float th = 0.049087385212340517f * (float)k;
    float s, c;
    sincosf(th, &s, &c);
    tw[k] = make_float2(c, -s);
}

__global__ void k_invd(const float* __restrict__ wr, const float* __restrict__ wi,
                       float2* __restrict__ invd1, float2* __restrict__ invd2) {
    int idx = blockIdx.x * 256 + threadIdx.x;
    int p  = idx & 15;
    int f  = (idx >> 4) & 15;
    int io = idx >> 8;
    const float W1 = 6.2340979026f;
    {
        float pr = wr[io * TOT + p], pim = wi[io * TOT + p];
        float dr = -pr, di = W1 * (float)f - pim;
        float s = 1.0f / (dr * dr + di * di);
        invd1[idx] = make_float2(dr * s, -di * s);
    }
    {
        float pr = wr[io * TOT + 16 + p], pim = wi[io * TOT + 16 + p];
        float dr = -pr, di = W1 * (float)f - pim;
        float s = 1.0f / (dr * dr + di * di);
        invd2[idx] = make_float2(dr * s, -di * s);
    }
}

// Fourier bf16 tables in the swizzled frag layout.
__global__ void k_tf(u16* __restrict__ fA, u16* __restrict__ fB) {
    for (int cidx = threadIdx.x; cidx < 1024; cidx += 256) {
        int tbl = cidx >> 9, mc = cidx & 511;
        int z = mc >> 2, cp = mc & 3;
        int c = cp ^ ((z >> 1) & 3);
        u16x8 v;
#pragma unroll
        for (int j = 0; j < 8; ++j) {
            int k = c * 8 + j, f = k & 15, part = k >> 4;
            float th = 0.049087385212340517f * (float)((f * z) & 127);
            float s, cs;
            sincosf(th, &s, &cs);
            float val = part ? ((tbl == 0) ? s : -s) : cs;
            v[j] = f2bf(val);
        }
        u16* dst = (tbl == 0 ? fA : fB) + mc * 8;
        *(u16x8*)dst = v;
    }
}

// Laplace exponent tables, bf16, pre-permuted for swizzled LDS frag reads.
// e1A[io][z][k]: k<16 -> Re e^(pole1_p * z/127) (p=k), k>=16 -> Im.
// e2B[io][x][k]: k<16 -> Re e^(pole2_q * x/127), k>=16 -> -Im.
__global__ __launch_bounds__(256) void k_ebf(const float* __restrict__ wr, const float* __restrict__ wi,
                                             u16* __restrict__ e1A, u16* __restrict__ e2B) {
    int io = blockIdx.x >> 1;
    int mc = (blockIdx.x & 1) * 256 + threadIdx.x;   // chunk in table
    int z = mc >> 2, cp = mc & 3;
    int c = cp ^ ((z >> 1) & 3);
    float t = (float)z * 0.007874015748031496f;      // z/127
    u16x8 v1, v2;
#pragma unroll
    for (int j = 0; j < 8; ++j) {
        int k = c * 8 + j, p = k & 15, part = k >> 4;
        {
            float pr = wr[io * TOT + p], pim = wi[io * TOT + p];
            float x = pr * t;
            float m = 1.f + x * (1.f + x * (0.5f + x * 0.16666667f));
            float th = pim * t, th2 = th * th;
            float sn = th * (1.f - th2 * 0.16666667f);
            float cs = 1.f - th2 * 0.5f;
            v1[j] = part ? f2bf(m * sn) : f2bf(m * cs);
        }
        {
            float pr = wr[io * TOT + 16 + p], pim = wi[io * TOT + 16 + p];
            float x = pr * t;
            float m = 1.f + x * (1.f + x * (0.5f + x * 0.16666667f));
            float th = pim * t, th2 = th * th;
            float sn = th * (1.f - th2 * 0.16666667f);
            float cs = 1.f - th2 * 0.5f;
            v2[j] = part ? f2bf(-(m * sn)) : f2bf(m * cs);
        }
    }
    *(u16x8*)(e1A + io * 4096 + mc * 8) = v1;
    *(u16x8*)(e2B + io * 4096 + mc * 8) = v2;
}

__global__ __launch_bounds__(256) void k_alpha(const float* __restrict__ x,
                                               const float2* __restrict__ tw,
                                               float2* __restrict__ alpha) {
    __shared__ float twr[128], twi[128];
    __shared__ float T1r[16][128], T1i[16][128];
    int t = threadIdx.x;
    int bi = blockIdx.x;
    if (t < 128) { float2 v = tw[t]; twr[t] = v.x; twi[t] = v.y; }
    __syncthreads();

    const float* xp = x + (size_t)bi * 16384;
    int xcol = t & 127;
    int f0 = (t >> 7) * 8;
    float ar[8], ai[8];
    int kk[8];
#pragma unroll
    for (int j = 0; j < 8; ++j) { ar[j] = 0.f; ai[j] = 0.f; kk[j] = 0; }
    for (int y = 0; y < 128; ++y) {
        float xv = xp[y * 128 + xcol];
#pragma unroll
        for (int j = 0; j < 8; ++j) {
            ar[j] += twr[kk[j]] * xv;
            ai[j] += twi[kk[j]] * xv;
            kk[j] = (kk[j] + f0 + j) & 127;
        }
    }
#pragma unroll
    for (int j = 0; j < 8; ++j) { T1r[f0 + j][xcol] = ar[j]; T1i[f0 + j][xcol] = ai[j]; }
    __syncthreads();

    int g = t & 15, f = t >> 4;
    float sr = 0.f, si = 0.f;
    int kg = 0;
    for (int xx = 0; xx < 128; ++xx) {
        float trv = T1r[f][xx], tiv = T1i[f][xx];
        float cr = twr[kg], ci = twi[kg];
        sr += trv * cr - tiv * ci;
        si += trv * ci + tiv * cr;
        kg = (kg + g) & 127;
    }
    alpha[bi * 256 + t] = make_float2(sr, si);
}

__global__ __launch_bounds__(256) void k_s1(const float* __restrict__ wr, const float* __restrict__ wi,
                                            const float2* __restrict__ invd1,
                                            const float2* __restrict__ invd2,
                                            float2* __restrict__ s1) {
    int io = blockIdx.x;
    int t = threadIdx.x;
    __shared__ float D1r[16][16], D1i[16][16];
    __shared__ float D2r[16][16], D2i[16][16];
    __shared__ float Rr[16][16], Ri[16][16];
    __shared__ float R1r[16][16], R1i[16][16];
    {
        float2 v1 = invd1[io * 256 + t]; D1r[t >> 4][t & 15] = v1.x; D1i[t >> 4][t & 15] = v1.y;
        float2 v2 = invd2[io * 256 + t]; D2r[t >> 4][t & 15] = v2.x; D2i[t >> 4][t & 15] = v2.y;
        Rr[t >> 4][t & 15] = wr[io * TOT + 32 + t];
        Ri[t >> 4][t & 15] = wi[io * TOT + 32 + t];
    }
    __syncthreads();
    int f = t >> 4, q = t & 15;
    float sr = 0.f, si = 0.f;
#pragma unroll
    for (int p = 0; p < 16; ++p) {
        float rr = Rr[p][q], ri = Ri[p][q];
        float dr = D1r[f][p], di = D1i[f][p];
        sr += rr * dr - ri * di;
        si += rr * di + ri * dr;
    }
    R1r[f][q] = sr; R1i[f][q] = si;
    __syncthreads();
    int g = t & 15;
    sr = 0.f; si = 0.f;
#pragma unroll
    for (int qq = 0; qq < 16; ++qq) {
        float rr = R1r[f][qq], ri = R1i[f][qq];
        float dr = D2r[g][qq], di = D2i[g][qq];
        sr += rr * dr - ri * di;
        si += rr * di + ri * dr;
    }
    s1[io * 256 + f * 16 + g] = make_float2(sr, si);
}

__global__ __launch_bounds__(256) void k_or1(const float2* __restrict__ alpha,
                                             const float2* __restrict__ s1,
                                             float2* __restrict__ or1) {
    int b = blockIdx.x >> 5, o = blockIdx.x & 31;
    int t = threadIdx.x;
    float sr = 0.f, si = 0.f;
    for (int i = 0; i < 32; ++i) {
        float2 a = alpha[(b * 32 + i) * 256 + t];
        float2 s = s1[(i * 32 + o) * 256 + t];
        sr += a.x * s.x - a.y * s.y;
        si += a.x * s.y + a.y * s.x;
    }
    or1[blockIdx.x * 256 + t] = make_float2(sr, si);
}

__global__ __launch_bounds__(256) void k_or2(const float* __restrict__ wr, const float* __restrict__ wi,
                                             const float2* __restrict__ alpha,
                                             const float2* __restrict__ invd1,
                                             const float2* __restrict__ invd2,
                                             float2* __restrict__ or2) {
    int b = blockIdx.x >> 5, o = blockIdx.x & 31;
    int t = threadIdx.x;
    __shared__ float Ar[16][16], Ai[16][16];
    __shared__ float D1r[16][16], D1i[16][16];
    __shared__ float D2r[16][16], D2i[16][16];
    __shared__ float Rr[16][16], Ri[16][16];
    __shared__ float Vr[16][16], Vi[16][16];
    int p_ = t >> 4, q_ = t & 15;
    float accr = 0.f, acci = 0.f;
    for (int i = 0; i < 32; ++i) {
        int io = i * 32 + o;
        float2 a  = alpha[(b * 32 + i) * 256 + t];
        float2 d1 = invd1[io * 256 + t];
        float2 d2 = invd2[io * 256 + t];
        float rr = wr[io * TOT + 32 + t];
        float ri = wi[io * TOT + 32 + t];
        __syncthreads();
        Ar[p_][q_] = a.x;  Ai[p_][q_] = a.y;
        D1r[p_][q_] = d1.x; D1i[p_][q_] = d1.y;
        D2r[p_][q_] = d2.x; D2i[p_][q_] = d2.y;
        Rr[p_][q_] = rr;   Ri[p_][q_] = ri;
        __syncthreads();
        float vr = 0.f, vi = 0.f;
#pragma unroll
        for (int f = 0; f < 16; ++f) {
            float ar2 = Ar[f][q_], ai2 = Ai[f][q_];
            float dr = D1r[f][p_], di = D1i[f][p_];
            vr += ar2 * dr - ai2 * di;
            vi += ar2 * di + ai2 * dr;
        }
        Vr[p_][q_] = vr; Vi[p_][q_] = vi;
        __syncthreads();
        float tr = 0.f, ti = 0.f;
#pragma unroll
        for (int g = 0; g < 16; ++g) {
            float vr2 = Vr[p_][g], vi2 = Vi[p_][g];
            float dr = D2r[g][q_], di = D2i[g][q_];
            tr += vr2 * dr - vi2 * di;
            ti += vr2 * di + vi2 * dr;
        }
        float rr2 = Rr[p_][q_], ri2 = Ri[p_][q_];
        accr += rr2 * tr - ri2 * ti;
        acci += rr2 * ti + ri2 * tr;
    }
    or2[blockIdx.x * 256 + t] = make_float2(accr, acci);
}

// MFMA final stage. Grid 512: bid -> o = bid&31, b = (bid>>5)&7, zh = bid>>8.
// Block covers z in [zh*64, zh*64+64), all 128 x, for one (b,o).
// 33 terms: term 0 = Fourier (M = or1), terms 1..32 = Laplace i (M = or2).
__global__ __launch_bounds__(512, 4) void k_x12m(
        const float2* __restrict__ or1v,
        const float2* __restrict__ or2v,
        const u16* __restrict__ e1A,
        const u16* __restrict__ e2B,
        const u16* __restrict__ fA,
        const u16* __restrict__ fB,
        float* __restrict__ out) {
    __shared__ u16 EA[2][2048];   // 64 z x 32 k
    __shared__ u16 EB[2][4096];   // 128 x x 32 k
    __shared__ u16 GL[2048];      // 64 z x 32 k

    const int t = threadIdx.x;
    const int l = t & 63, w = t >> 6;
    const int bid = blockIdx.x;
    const int o = bid & 31, b = (bid >> 5) & 7, zh = bid >> 8;
    const int bo = b * 32 + o;
    const int q = l & 15, c4 = l >> 4, k0 = c4 * 8;

    // --- M fragments (B operand of G-phase), kept in registers for all terms ---
    short8 mF0, mF1, mL0, mL1;
    {
        const float2* M1 = or1v + bo * 256;
        const float2* M2 = or2v + bo * 256;
#pragma unroll
        for (int j = 0; j < 8; ++j) {
            int k = k0 + j;
            int f = k & 15;
            float2 m1 = M1[f * 16 + q];
            float2 m2 = M2[f * 16 + q];
            if (k < 16) {
                mF0[j] = (short)f2bf(m1.x); mF1[j] = (short)f2bf(m1.y);
                mL0[j] = (short)f2bf(m2.x); mL1[j] = (short)f2bf(m2.y);
            } else {
                mF0[j] = (short)f2bf(-m1.y); mF1[j] = (short)f2bf(m1.x);
                mL0[j] = (short)f2bf(-m2.y); mL1[j] = (short)f2bf(m2.x);
            }
        }
    }

    f32x4 acc[4];
#pragma unroll
    for (int zt = 0; zt < 4; ++zt) acc[zt] = (f32x4){0.f, 0.f, 0.f, 0.f};

    auto do_stage = [&](int term, int buf) {
        const u16* sA;
        const u16* sB;
        if (term == 0) { sA = fA + zh * 2048; sB = fB; }
        else { int io = (term - 1) * 32 + o; sA = e1A + io * 4096 + zh * 2048; sB = e2B + io * 4096; }
        for (int ch = w; ch < 12; ch += 8) {
            const u16* g;
            u16* d;
            if (ch < 4) { g = sA + ch * 512 + l * 8; d = &EA[buf][ch * 512]; }
            else { g = sB + (ch - 4) * 512 + l * 8; d = &EB[buf][(ch - 4) * 512]; }
            __builtin_amdgcn_global_load_lds(
                (const __attribute__((address_space(1))) unsigned*)g,
                (__attribute__((address_space(3))) unsigned*)d, 16, 0, 0);
        }
    };

    do_stage(0, 0);
    __syncthreads();

    for (int term = 0; term < 33; ++term) {
        int cur = term & 1;
        // --- G phase: wave w computes z-tile (w>>1), part (w&1) ---
        {
            int zt = w >> 1;
            int zL = zt * 16 + q;
            int cw = c4 ^ ((zL >> 1) & 3);
            short8 aG = *(const short8*)&EA[cur][zL * 32 + cw * 8];
            short8 b0 = term ? mL0 : mF0;
            short8 b1 = term ? mL1 : mF1;
            short8 bG = (w & 1) ? b1 : b0;
            f32x4 g = (f32x4){0.f, 0.f, 0.f, 0.f};
            g = __builtin_amdgcn_mfma_f32_16x16x32_bf16(aG, bG, g, 0, 0, 0);
            int kk = q + ((w & 1) << 4);
#pragma unroll
            for (int r = 0; r < 4; ++r) {
                int zz = zt * 16 + c4 * 4 + r;
                int cc = (kk >> 3) ^ ((zz >> 1) & 3);
                GL[zz * 32 + cc * 8 + (kk & 7)] = f2bf(g[r]);
            }
        }
        __syncthreads();
        // prefetch next term (overlaps inner phase; drained at end-of-term barrier)
        if (term + 1 < 33) do_stage(term + 1, cur ^ 1);
        // --- inner phase: wave w owns x-tile w ---
        {
            int x = w * 16 + q;
            int cb = c4 ^ ((x >> 1) & 3);
            short8 bf = *(const short8*)&EB[cur][x * 32 + cb * 8];
#pragma unroll
            for (int zt = 0; zt < 4; ++zt) {
                int zL = zt * 16 + q;
                int ca = c4 ^ ((zL >> 1) & 3);
                short8 af = *(const short8*)&GL[zL * 32 + ca * 8];
                acc[zt] = __builtin_amdgcn_mfma_f32_16x16x32_bf16(af, bf, acc[zt], 0, 0, 0);
            }
        }
        __syncthreads();
    }

    const float sc = 1.0f / 16384.0f;
    int x = w * 16 + q;
#pragma unroll
    for (int zt = 0; zt < 4; ++zt) {
        int zbase = zh * 64 + zt * 16 + c4 * 4;
        f32x4 a = acc[zt];
#pragma unroll
        for (int r = 0; r < 4; ++r)
            out[(size_t)bo * 16384 + (zbase + r) * 128 + x] = a[r] * sc;
    }
}

extern "C" void kernel_launch(void* const* d_in, const int* in_sizes, int n_in,
                              void* d_out, int out_size, void* d_ws, size_t ws_size,
                              hipStream_t stream) {
    const float* x  = (const float*)d_in[0];
    const float* wr = (const float*)d_in[1];
    const float* wi = (const float*)d_in[2];
    float* out = (float*)d_out;
    float* ws = (float*)d_ws;

    float2* tw    = (float2*)(ws + 0);
    float2* alpha = (float2*)(ws + 256);
    float2* invd1 = (float2*)(ws + 131328);
    float2* invd2 = (float2*)(ws + 655616);
    float2* s1    = (float2*)(ws + 1179904);
    float2* or1   = (float2*)(ws + 1704192);
    float2* or2   = (float2*)(ws + 1835264);
    u16*    e1A   = (u16*)(ws + 1966336);
    u16*    e2B   = (u16*)(ws + 4063488);
    u16*    fA    = (u16*)(ws + 6160640);
    u16*    fB    = (u16*)(ws + 6162688);

    hipLaunchKernelGGL(k_tw,    dim3(1),    dim3(128), 0, stream, tw);
    hipLaunchKernelGGL(k_invd,  dim3(1024), dim3(256), 0, stream, wr, wi, invd1, invd2);
    hipLaunchKernelGGL(k_tf,    dim3(1),    dim3(256), 0, stream, fA, fB);
    hipLaunchKernelGGL(k_ebf,   dim3(2048), dim3(256), 0, stream, wr, wi, e1A, e2B);
    hipLaunchKernelGGL(k_alpha, dim3(256),  dim3(256), 0, stream, x, tw, alpha);
    hipLaunchKernelGGL(k_s1,    dim3(1024), dim3(256), 0, stream, wr, wi, invd1, invd2, s1);
    hipLaunchKernelGGL(k_or1,   dim3(256),  dim3(256), 0, stream, alpha, s1, or1);
    hipLaunchKernelGGL(k_or2,   dim3(256),  dim3(256), 0, stream, wr, wi, alpha, invd1, invd2, or2);
    hipLaunchKernelGGL(k_x12m,  dim3(512),  dim3(512), 0, stream, or1, or2, e1A, e2B, fA, fB, out);
}

// Round 3
// 116.121 us; speedup vs baseline: 3.2514x; 1.1249x over previous
//
#include <hip/hip_runtime.h>

#define TOT 288

typedef short short8 __attribute__((ext_vector_type(8)));
typedef float f32x4 __attribute__((ext_vector_type(4)));
typedef unsigned short u16;
typedef u16 u16x8 __attribute__((ext_vector_type(8)));

__device__ __forceinline__ u16 f2bf(float f) {
    unsigned u = __builtin_bit_cast(unsigned, f);
    u += 0x7fffu + ((u >> 16) & 1u);
    return (u16)(u >> 16);
}

// ---------------- workspace layout (float offsets) ----------------
// tw     :        0  (256)
// alpha  :      256  (131072)       [b][i][f][g] float2
// invd1  :   131328  (524288)       [i][o][f][p] float2
// invd2  :   655616  (524288)       [i][o][g][q] float2
// s1     :  1179904  (524288)       [i][o][f][g] float2
// or1    :  1704192  (131072)       [b][o][f][g] float2
// or2    :  1835264  (131072)       [b][o][p][q] float2
// e1A    :  1966336  (2097152)      bf16 [io][128z][32k] swizzled (A-frag layout)
// e2B    :  4063488  (2097152)      bf16 [io][128x][32k] swizzled (B-frag, k>=16 negated imag)
// fA     :  6160640  (2048)         bf16 Fourier A table
// fB     :  6162688  (2048)         bf16 Fourier B table
// or2p   :  6164736  (1048576)      partial or2 [ic=8][bo=256][pq=256] float2

__global__ void k_tw(float2* __restrict__ tw) {
    int k = threadIdx.x;
    float th = 0.049087385212340517f * (float)k;
    float s, c;
    sincosf(th, &s, &c);
    tw[k] = make_float2(c, -s);
}

__global__ void k_invd(const float* __restrict__ wr, const float* __restrict__ wi,
                       float2* __restrict__ invd1, float2* __restrict__ invd2) {
    int idx = blockIdx.x * 256 + threadIdx.x;
    int p  = idx & 15;
    int f  = (idx >> 4) & 15;
    int io = idx >> 8;
    const float W1 = 6.2340979026f;
    {
        float pr = wr[io * TOT + p], pim = wi[io * TOT + p];
        float dr = -pr, di = W1 * (float)f - pim;
        float s = 1.0f / (dr * dr + di * di);
        invd1[idx] = make_float2(dr * s, -di * s);
    }
    {
        float pr = wr[io * TOT + 16 + p], pim = wi[io * TOT + 16 + p];
        float dr = -pr, di = W1 * (float)f - pim;
        float s = 1.0f / (dr * dr + di * di);
        invd2[idx] = make_float2(dr * s, -di * s);
    }
}

__global__ void k_tf(u16* __restrict__ fA, u16* __restrict__ fB) {
    for (int cidx = threadIdx.x; cidx < 1024; cidx += 256) {
        int tbl = cidx >> 9, mc = cidx & 511;
        int z = mc >> 2, cp = mc & 3;
        int c = cp ^ ((z >> 1) & 3);
        u16x8 v;
#pragma unroll
        for (int j = 0; j < 8; ++j) {
            int k = c * 8 + j, f = k & 15, part = k >> 4;
            float th = 0.049087385212340517f * (float)((f * z) & 127);
            float s, cs;
            sincosf(th, &s, &cs);
            float val = part ? ((tbl == 0) ? s : -s) : cs;
            v[j] = f2bf(val);
        }
        u16* dst = (tbl == 0 ? fA : fB) + mc * 8;
        *(u16x8*)dst = v;
    }
}

__global__ __launch_bounds__(256) void k_ebf(const float* __restrict__ wr, const float* __restrict__ wi,
                                             u16* __restrict__ e1A, u16* __restrict__ e2B) {
    int io = blockIdx.x >> 1;
    int mc = (blockIdx.x & 1) * 256 + threadIdx.x;
    int z = mc >> 2, cp = mc & 3;
    int c = cp ^ ((z >> 1) & 3);
    float t = (float)z * 0.007874015748031496f;
    u16x8 v1, v2;
#pragma unroll
    for (int j = 0; j < 8; ++j) {
        int k = c * 8 + j, p = k & 15, part = k >> 4;
        {
            float pr = wr[io * TOT + p], pim = wi[io * TOT + p];
            float x = pr * t;
            float m = 1.f + x * (1.f + x * (0.5f + x * 0.16666667f));
            float th = pim * t, th2 = th * th;
            float sn = th * (1.f - th2 * 0.16666667f);
            float cs = 1.f - th2 * 0.5f;
            v1[j] = part ? f2bf(m * sn) : f2bf(m * cs);
        }
        {
            float pr = wr[io * TOT + 16 + p], pim = wi[io * TOT + 16 + p];
            float x = pr * t;
            float m = 1.f + x * (1.f + x * (0.5f + x * 0.16666667f));
            float th = pim * t, th2 = th * th;
            float sn = th * (1.f - th2 * 0.16666667f);
            float cs = 1.f - th2 * 0.5f;
            v2[j] = part ? f2bf(-(m * sn)) : f2bf(m * cs);
        }
    }
    *(u16x8*)(e1A + io * 4096 + mc * 8) = v1;
    *(u16x8*)(e2B + io * 4096 + mc * 8) = v2;
}

__global__ __launch_bounds__(256) void k_alpha(const float* __restrict__ x,
                                               const float2* __restrict__ tw,
                                               float2* __restrict__ alpha) {
    __shared__ float twr[128], twi[128];
    __shared__ float T1r[16][128], T1i[16][128];
    int t = threadIdx.x;
    int bi = blockIdx.x;
    if (t < 128) { float2 v = tw[t]; twr[t] = v.x; twi[t] = v.y; }
    __syncthreads();

    const float* xp = x + (size_t)bi * 16384;
    int xcol = t & 127;
    int f0 = (t >> 7) * 8;
    float ar[8], ai[8];
    int kk[8];
#pragma unroll
    for (int j = 0; j < 8; ++j) { ar[j] = 0.f; ai[j] = 0.f; kk[j] = 0; }
    for (int y = 0; y < 128; ++y) {
        float xv = xp[y * 128 + xcol];
#pragma unroll
        for (int j = 0; j < 8; ++j) {
            ar[j] += twr[kk[j]] * xv;
            ai[j] += twi[kk[j]] * xv;
            kk[j] = (kk[j] + f0 + j) & 127;
        }
    }
#pragma unroll
    for (int j = 0; j < 8; ++j) { T1r[f0 + j][xcol] = ar[j]; T1i[f0 + j][xcol] = ai[j]; }
    __syncthreads();

    int g = t & 15, f = t >> 4;
    float sr = 0.f, si = 0.f;
    int kg = 0;
    for (int xx = 0; xx < 128; ++xx) {
        float trv = T1r[f][xx], tiv = T1i[f][xx];
        float cr = twr[kg], ci = twi[kg];
        sr += trv * cr - tiv * ci;
        si += trv * ci + tiv * cr;
        kg = (kg + g) & 127;
    }
    alpha[bi * 256 + t] = make_float2(sr, si);
}

__global__ __launch_bounds__(256) void k_s1(const float* __restrict__ wr, const float* __restrict__ wi,
                                            const float2* __restrict__ invd1,
                                            const float2* __restrict__ invd2,
                                            float2* __restrict__ s1) {
    int io = blockIdx.x;
    int t = threadIdx.x;
    __shared__ float D1r[16][16], D1i[16][16];
    __shared__ float D2r[16][16], D2i[16][16];
    __shared__ float Rr[16][16], Ri[16][16];
    __shared__ float R1r[16][16], R1i[16][16];
    {
        float2 v1 = invd1[io * 256 + t]; D1r[t >> 4][t & 15] = v1.x; D1i[t >> 4][t & 15] = v1.y;
        float2 v2 = invd2[io * 256 + t]; D2r[t >> 4][t & 15] = v2.x; D2i[t >> 4][t & 15] = v2.y;
        Rr[t >> 4][t & 15] = wr[io * TOT + 32 + t];
        Ri[t >> 4][t & 15] = wi[io * TOT + 32 + t];
    }
    __syncthreads();
    int f = t >> 4, q = t & 15;
    float sr = 0.f, si = 0.f;
#pragma unroll
    for (int p = 0; p < 16; ++p) {
        float rr = Rr[p][q], ri = Ri[p][q];
        float dr = D1r[f][p], di = D1i[f][p];
        sr += rr * dr - ri * di;
        si += rr * di + ri * dr;
    }
    R1r[f][q] = sr; R1i[f][q] = si;
    __syncthreads();
    int g = t & 15;
    sr = 0.f; si = 0.f;
#pragma unroll
    for (int qq = 0; qq < 16; ++qq) {
        float rr = R1r[f][qq], ri = R1i[f][qq];
        float dr = D2r[g][qq], di = D2i[g][qq];
        sr += rr * dr - ri * di;
        si += rr * di + ri * dr;
    }
    s1[io * 256 + f * 16 + g] = make_float2(sr, si);
}

__global__ __launch_bounds__(256) void k_or1(const float2* __restrict__ alpha,
                                             const float2* __restrict__ s1,
                                             float2* __restrict__ or1) {
    int b = blockIdx.x >> 5, o = blockIdx.x & 31;
    int t = threadIdx.x;
    float sr = 0.f, si = 0.f;
    for (int i = 0; i < 32; ++i) {
        float2 a = alpha[(b * 32 + i) * 256 + t];
        float2 s = s1[(i * 32 + o) * 256 + t];
        sr += a.x * s.x - a.y * s.y;
        si += a.x * s.y + a.y * s.x;
    }
    or1[blockIdx.x * 256 + t] = make_float2(sr, si);
}

// Partial or2: block = (ic, b, o); handles i in [ic*4, ic*4+4).
__global__ __launch_bounds__(256) void k_or2p(const float* __restrict__ wr, const float* __restrict__ wi,
                                              const float2* __restrict__ alpha,
                                              const float2* __restrict__ invd1,
                                              const float2* __restrict__ invd2,
                                              float2* __restrict__ or2p) {
    int bo = blockIdx.x & 255;
    int ic = blockIdx.x >> 8;
    int b = bo >> 5, o = bo & 31;
    int t = threadIdx.x;
    __shared__ float Ar[16][16], Ai[16][16];
    __shared__ float D1r[16][16], D1i[16][16];
    __shared__ float D2r[16][16], D2i[16][16];
    __shared__ float Rr[16][16], Ri[16][16];
    __shared__ float Vr[16][16], Vi[16][16];
    int p_ = t >> 4, q_ = t & 15;
    float accr = 0.f, acci = 0.f;
    for (int ii = 0; ii < 4; ++ii) {
        int i = ic * 4 + ii;
        int io = i * 32 + o;
        float2 a  = alpha[(b * 32 + i) * 256 + t];
        float2 d1 = invd1[io * 256 + t];
        float2 d2 = invd2[io * 256 + t];
        float rr = wr[io * TOT + 32 + t];
        float ri = wi[io * TOT + 32 + t];
        __syncthreads();
        Ar[p_][q_] = a.x;  Ai[p_][q_] = a.y;
        D1r[p_][q_] = d1.x; D1i[p_][q_] = d1.y;
        D2r[p_][q_] = d2.x; D2i[p_][q_] = d2.y;
        Rr[p_][q_] = rr;   Ri[p_][q_] = ri;
        __syncthreads();
        float vr = 0.f, vi = 0.f;
#pragma unroll
        for (int f = 0; f < 16; ++f) {
            float ar2 = Ar[f][q_], ai2 = Ai[f][q_];
            float dr = D1r[f][p_], di = D1i[f][p_];
            vr += ar2 * dr - ai2 * di;
            vi += ar2 * di + ai2 * dr;
        }
        Vr[p_][q_] = vr; Vi[p_][q_] = vi;
        __syncthreads();
        float tr = 0.f, ti = 0.f;
#pragma unroll
        for (int g = 0; g < 16; ++g) {
            float vr2 = Vr[p_][g], vi2 = Vi[p_][g];
            float dr = D2r[g][q_], di = D2i[g][q_];
            tr += vr2 * dr - vi2 * di;
            ti += vr2 * di + vi2 * dr;
        }
        float rr2 = Rr[p_][q_], ri2 = Ri[p_][q_];
        accr += rr2 * tr - ri2 * ti;
        acci += rr2 * ti + ri2 * tr;
    }
    or2p[(size_t)ic * 65536 + bo * 256 + t] = make_float2(accr, acci);
}

// Reduce 8 partials -> or2 (fixed order, deterministic).
__global__ __launch_bounds__(256) void k_or2r(const float2* __restrict__ or2p,
                                              float2* __restrict__ or2) {
    int idx = blockIdx.x * 256 + threadIdx.x;
    float sr = 0.f, si = 0.f;
#pragma unroll
    for (int ic = 0; ic < 8; ++ic) {
        float2 v = or2p[(size_t)ic * 65536 + idx];
        sr += v.x; si += v.y;
    }
    or2[idx] = make_float2(sr, si);
}

// MFMA final stage (unchanged from round 2).
__global__ __launch_bounds__(512, 4) void k_x12m(
        const float2* __restrict__ or1v,
        const float2* __restrict__ or2v,
        const u16* __restrict__ e1A,
        const u16* __restrict__ e2B,
        const u16* __restrict__ fA,
        const u16* __restrict__ fB,
        float* __restrict__ out) {
    __shared__ u16 EA[2][2048];
    __shared__ u16 EB[2][4096];
    __shared__ u16 GL[2048];

    const int t = threadIdx.x;
    const int l = t & 63, w = t >> 6;
    const int bid = blockIdx.x;
    const int o = bid & 31, b = (bid >> 5) & 7, zh = bid >> 8;
    const int bo = b * 32 + o;
    const int q = l & 15, c4 = l >> 4, k0 = c4 * 8;

    short8 mF0, mF1, mL0, mL1;
    {
        const float2* M1 = or1v + bo * 256;
        const float2* M2 = or2v + bo * 256;
#pragma unroll
        for (int j = 0; j < 8; ++j) {
            int k = k0 + j;
            int f = k & 15;
            float2 m1 = M1[f * 16 + q];
            float2 m2 = M2[f * 16 + q];
            if (k < 16) {
                mF0[j] = (short)f2bf(m1.x); mF1[j] = (short)f2bf(m1.y);
                mL0[j] = (short)f2bf(m2.x); mL1[j] = (short)f2bf(m2.y);
            } else {
                mF0[j] = (short)f2bf(-m1.y); mF1[j] = (short)f2bf(m1.x);
                mL0[j] = (short)f2bf(-m2.y); mL1[j] = (short)f2bf(m2.x);
            }
        }
    }

    f32x4 acc[4];
#pragma unroll
    for (int zt = 0; zt < 4; ++zt) acc[zt] = (f32x4){0.f, 0.f, 0.f, 0.f};

    auto do_stage = [&](int term, int buf) {
        const u16* sA;
        const u16* sB;
        if (term == 0) { sA = fA + zh * 2048; sB = fB; }
        else { int io = (term - 1) * 32 + o; sA = e1A + io * 4096 + zh * 2048; sB = e2B + io * 4096; }
        for (int ch = w; ch < 12; ch += 8) {
            const u16* g;
            u16* d;
            if (ch < 4) { g = sA + ch * 512 + l * 8; d = &EA[buf][ch * 512]; }
            else { g = sB + (ch - 4) * 512 + l * 8; d = &EB[buf][(ch - 4) * 512]; }
            __builtin_amdgcn_global_load_lds(
                (const __attribute__((address_space(1))) unsigned*)g,
                (__attribute__((address_space(3))) unsigned*)d, 16, 0, 0);
        }
    };

    do_stage(0, 0);
    __syncthreads();

    for (int term = 0; term < 33; ++term) {
        int cur = term & 1;
        {
            int zt = w >> 1;
            int zL = zt * 16 + q;
            int cw = c4 ^ ((zL >> 1) & 3);
            short8 aG = *(const short8*)&EA[cur][zL * 32 + cw * 8];
            short8 b0 = term ? mL0 : mF0;
            short8 b1 = term ? mL1 : mF1;
            short8 bG = (w & 1) ? b1 : b0;
            f32x4 g = (f32x4){0.f, 0.f, 0.f, 0.f};
            g = __builtin_amdgcn_mfma_f32_16x16x32_bf16(aG, bG, g, 0, 0, 0);
            int kk = q + ((w & 1) << 4);
#pragma unroll
            for (int r = 0; r < 4; ++r) {
                int zz = zt * 16 + c4 * 4 + r;
                int cc = (kk >> 3) ^ ((zz >> 1) & 3);
                GL[zz * 32 + cc * 8 + (kk & 7)] = f2bf(g[r]);
            }
        }
        __syncthreads();
        if (term + 1 < 33) do_stage(term + 1, cur ^ 1);
        {
            int x = w * 16 + q;
            int cb = c4 ^ ((x >> 1) & 3);
            short8 bf = *(const short8*)&EB[cur][x * 32 + cb * 8];
#pragma unroll
            for (int zt = 0; zt < 4; ++zt) {
                int zL = zt * 16 + q;
                int ca = c4 ^ ((zL >> 1) & 3);
                short8 af = *(const short8*)&GL[zL * 32 + ca * 8];
                acc[zt] = __builtin_amdgcn_mfma_f32_16x16x32_bf16(af, bf, acc[zt], 0, 0, 0);
            }
        }
        __syncthreads();
    }

    const float sc = 1.0f / 16384.0f;
    int x = w * 16 + q;
#pragma unroll
    for (int zt = 0; zt < 4; ++zt) {
        int zbase = zh * 64 + zt * 16 + c4 * 4;
        f32x4 a = acc[zt];
#pragma unroll
        for (int r = 0; r < 4; ++r)
            out[(size_t)bo * 16384 + (zbase + r) * 128 + x] = a[r] * sc;
    }
}

extern "C" void kernel_launch(void* const* d_in, const int* in_sizes, int n_in,
                              void* d_out, int out_size, void* d_ws, size_t ws_size,
                              hipStream_t stream) {
    const float* x  = (const float*)d_in[0];
    const float* wr = (const float*)d_in[1];
    const float* wi = (const float*)d_in[2];
    float* out = (float*)d_out;
    float* ws = (float*)d_ws;

    float2* tw    = (float2*)(ws + 0);
    float2* alpha = (float2*)(ws + 256);
    float2* invd1 = (float2*)(ws + 131328);
    float2* invd2 = (float2*)(ws + 655616);
    float2* s1    = (float2*)(ws + 1179904);
    float2* or1   = (float2*)(ws + 1704192);
    float2* or2   = (float2*)(ws + 1835264);
    u16*    e1A   = (u16*)(ws + 1966336);
    u16*    e2B   = (u16*)(ws + 4063488);
    u16*    fA    = (u16*)(ws + 6160640);
    u16*    fB    = (u16*)(ws + 6162688);
    float2* or2p  = (float2*)(ws + 6164736);

    hipLaunchKernelGGL(k_tw,    dim3(1),    dim3(128), 0, stream, tw);
    hipLaunchKernelGGL(k_invd,  dim3(1024), dim3(256), 0, stream, wr, wi, invd1, invd2);
    hipLaunchKernelGGL(k_tf,    dim3(1),    dim3(256), 0, stream, fA, fB);
    hipLaunchKernelGGL(k_ebf,   dim3(2048), dim3(256), 0, stream, wr, wi, e1A, e2B);
    hipLaunchKernelGGL(k_alpha, dim3(256),  dim3(256), 0, stream, x, tw, alpha);
    hipLaunchKernelGGL(k_s1,    dim3(1024), dim3(256), 0, stream, wr, wi, invd1, invd2, s1);
    hipLaunchKernelGGL(k_or1,   dim3(256),  dim3(256), 0, stream, alpha, s1, or1);
    hipLaunchKernelGGL(k_or2p,  dim3(2048), dim3(256), 0, stream, wr, wi, alpha, invd1, invd2, or2p);
    hipLaunchKernelGGL(k_or2r,  dim3(256),  dim3(256), 0, stream, or2p, or2);
    hipLaunchKernelGGL(k_x12m,  dim3(512),  dim3(512), 0, stream, or1, or2, e1A, e2B, fA, fB, out);
}

// Round 4
// 113.644 us; speedup vs baseline: 3.3223x; 1.0218x over previous
//
#include <hip/hip_runtime.h>

#define TOT 288

typedef short short8 __attribute__((ext_vector_type(8)));
typedef float f32x4 __attribute__((ext_vector_type(4)));
typedef unsigned short u16;
typedef u16 u16x8 __attribute__((ext_vector_type(8)));

__device__ __forceinline__ u16 f2bf(float f) {
    unsigned u = __builtin_bit_cast(unsigned, f);
    u += 0x7fffu + ((u >> 16) & 1u);
    return (u16)(u >> 16);
}

// ---------------- workspace layout (float offsets) ----------------
// alpha  :      256  (131072)       [b][i][f][g] float2
// s1     :  1179904  (524288)       [i][o][f][g] float2
// or1    :  1704192  (131072)       [b][o][f][g] float2
// e1A    :  1966336  (2097152)      bf16 [io][128z][32k] swizzled (A-frag layout)
// e2B    :  4063488  (2097152)      bf16 [io][128x][32k] swizzled (B-frag, k>=16 negated imag)
// fA     :  6160640  (2048)         bf16 Fourier A table
// fB     :  6162688  (2048)         bf16 Fourier B table
// or2p   :  6164736  (1048576)      partial or2 [ic=8][bo=256][pq=256] float2

// ============ k_pre: ebf (0..2047) | tf (2048) | alpha (2049..2304) | s1 (2305..3328)
__global__ __launch_bounds__(256) void k_pre(const float* __restrict__ x,
                                             const float* __restrict__ wr,
                                             const float* __restrict__ wi,
                                             u16* __restrict__ e1A, u16* __restrict__ e2B,
                                             u16* __restrict__ fA, u16* __restrict__ fB,
                                             float2* __restrict__ alpha,
                                             float2* __restrict__ s1) {
    __shared__ float sm[4352];
    const int bid = blockIdx.x;
    const int t = threadIdx.x;

    if (bid < 2048) {
        // ----- ebf: Laplace exponent tables, bf16, frag-swizzled -----
        int io = bid >> 1;
        int mc = (bid & 1) * 256 + t;
        int z = mc >> 2, cp = mc & 3;
        int c = cp ^ ((z >> 1) & 3);
        float tt = (float)z * 0.007874015748031496f;
        u16x8 v1, v2;
#pragma unroll
        for (int j = 0; j < 8; ++j) {
            int k = c * 8 + j, p = k & 15, part = k >> 4;
            {
                float pr = wr[io * TOT + p], pim = wi[io * TOT + p];
                float xx = pr * tt;
                float m = 1.f + xx * (1.f + xx * (0.5f + xx * 0.16666667f));
                float th = pim * tt, th2 = th * th;
                float sn = th * (1.f - th2 * 0.16666667f);
                float cs = 1.f - th2 * 0.5f;
                v1[j] = part ? f2bf(m * sn) : f2bf(m * cs);
            }
            {
                float pr = wr[io * TOT + 16 + p], pim = wi[io * TOT + 16 + p];
                float xx = pr * tt;
                float m = 1.f + xx * (1.f + xx * (0.5f + xx * 0.16666667f));
                float th = pim * tt, th2 = th * th;
                float sn = th * (1.f - th2 * 0.16666667f);
                float cs = 1.f - th2 * 0.5f;
                v2[j] = part ? f2bf(-(m * sn)) : f2bf(m * cs);
            }
        }
        *(u16x8*)(e1A + io * 4096 + mc * 8) = v1;
        *(u16x8*)(e2B + io * 4096 + mc * 8) = v2;
    } else if (bid == 2048) {
        // ----- tf: Fourier bf16 tables -----
        for (int cidx = t; cidx < 1024; cidx += 256) {
            int tbl = cidx >> 9, mc = cidx & 511;
            int z = mc >> 2, cp = mc & 3;
            int c = cp ^ ((z >> 1) & 3);
            u16x8 v;
#pragma unroll
            for (int j = 0; j < 8; ++j) {
                int k = c * 8 + j, f = k & 15, part = k >> 4;
                float th = 0.049087385212340517f * (float)((f * z) & 127);
                float s, cs;
                sincosf(th, &s, &cs);
                float val = part ? ((tbl == 0) ? s : -s) : cs;
                v[j] = f2bf(val);
            }
            u16* dst = (tbl == 0 ? fA : fB) + mc * 8;
            *(u16x8*)dst = v;
        }
    } else if (bid < 2305) {
        // ----- alpha: partial 2D DFT corner -----
        float* twr = sm;            // 128
        float* twi = sm + 128;      // 128
        float* T1r = sm + 256;      // 16*128
        float* T1i = sm + 2304;     // 16*128
        int bi = bid - 2049;
        if (t < 128) {
            float s, c;
            sincosf(0.049087385212340517f * (float)t, &s, &c);
            twr[t] = c; twi[t] = -s;
        }
        __syncthreads();

        const float* xp = x + (size_t)bi * 16384;
        int xcol = t & 127;
        int f0 = (t >> 7) * 8;
        float ar[8], ai[8];
        int kk[8];
#pragma unroll
        for (int j = 0; j < 8; ++j) { ar[j] = 0.f; ai[j] = 0.f; kk[j] = 0; }
        for (int y = 0; y < 128; ++y) {
            float xv = xp[y * 128 + xcol];
#pragma unroll
            for (int j = 0; j < 8; ++j) {
                ar[j] += twr[kk[j]] * xv;
                ai[j] += twi[kk[j]] * xv;
                kk[j] = (kk[j] + f0 + j) & 127;
            }
        }
#pragma unroll
        for (int j = 0; j < 8; ++j) { T1r[(f0 + j) * 128 + xcol] = ar[j]; T1i[(f0 + j) * 128 + xcol] = ai[j]; }
        __syncthreads();

        int g = t & 15, f = t >> 4;
        float sr = 0.f, si = 0.f;
        int kg = 0;
        for (int xx = 0; xx < 128; ++xx) {
            float trv = T1r[f * 128 + xx], tiv = T1i[f * 128 + xx];
            float cr = twr[kg], ci = twi[kg];
            sr += trv * cr - tiv * ci;
            si += trv * ci + tiv * cr;
            kg = (kg + g) & 127;
        }
        alpha[bi * 256 + t] = make_float2(sr, si);
    } else {
        // ----- s1 (inline invd): s1[io][f][g] -----
        float* D1r = sm;        float* D1i = sm + 256;
        float* D2r = sm + 512;  float* D2i = sm + 768;
        float* Rr  = sm + 1024; float* Ri  = sm + 1280;
        float* R1r = sm + 1536; float* R1i = sm + 1792;
        int io = bid - 2305;
        const float W1 = 6.2340979026f;
        {
            int p = t & 15, f = t >> 4;
            {
                float pr = wr[io * TOT + p], pim = wi[io * TOT + p];
                float dr = -pr, di = W1 * (float)f - pim;
                float s = 1.0f / (dr * dr + di * di);
                D1r[t] = dr * s; D1i[t] = -di * s;
            }
            {
                float pr = wr[io * TOT + 16 + p], pim = wi[io * TOT + 16 + p];
                float dr = -pr, di = W1 * (float)f - pim;
                float s = 1.0f / (dr * dr + di * di);
                D2r[t] = dr * s; D2i[t] = -di * s;
            }
            Rr[t] = wr[io * TOT + 32 + t];
            Ri[t] = wi[io * TOT + 32 + t];
        }
        __syncthreads();
        int f = t >> 4, q = t & 15;
        float sr = 0.f, si = 0.f;
#pragma unroll
        for (int p = 0; p < 16; ++p) {
            float rr = Rr[p * 16 + q], ri = Ri[p * 16 + q];
            float dr = D1r[f * 16 + p], di = D1i[f * 16 + p];
            sr += rr * dr - ri * di;
            si += rr * di + ri * dr;
        }
        R1r[t] = sr; R1i[t] = si;
        __syncthreads();
        int g = t & 15;
        sr = 0.f; si = 0.f;
#pragma unroll
        for (int qq = 0; qq < 16; ++qq) {
            float rr = R1r[f * 16 + qq], ri = R1i[f * 16 + qq];
            float dr = D2r[g * 16 + qq], di = D2i[g * 16 + qq];
            sr += rr * dr - ri * di;
            si += rr * di + ri * dr;
        }
        s1[io * 256 + f * 16 + g] = make_float2(sr, si);
    }
}

// ============ k_mid: or2p (0..2047) | or1 (2048..2303)
__global__ __launch_bounds__(256) void k_mid(const float* __restrict__ wr,
                                             const float* __restrict__ wi,
                                             const float2* __restrict__ alpha,
                                             const float2* __restrict__ s1,
                                             float2* __restrict__ or1,
                                             float2* __restrict__ or2p) {
    __shared__ float sm[2560];
    const int bid = blockIdx.x;
    const int t = threadIdx.x;

    if (bid < 2048) {
        // ----- or2 partial (inline invd): i in [ic*4, ic*4+4) -----
        float* Ar  = sm;        float* Ai  = sm + 256;
        float* D1r = sm + 512;  float* D1i = sm + 768;
        float* D2r = sm + 1024; float* D2i = sm + 1280;
        float* Rr  = sm + 1536; float* Ri  = sm + 1792;
        float* Vr  = sm + 2048; float* Vi  = sm + 2304;
        int bo = bid & 255;
        int ic = bid >> 8;
        int b = bo >> 5, o = bo & 31;
        int p_ = t >> 4, q_ = t & 15;
        const float W1 = 6.2340979026f;
        float accr = 0.f, acci = 0.f;
        for (int ii = 0; ii < 4; ++ii) {
            int i = ic * 4 + ii;
            int io = i * 32 + o;
            float2 a = alpha[(b * 32 + i) * 256 + t];
            float d1x, d1y, d2x, d2y;
            {
                float pr = wr[io * TOT + q_], pim = wi[io * TOT + q_];
                float dr = -pr, di = W1 * (float)p_ - pim;
                float s = 1.0f / (dr * dr + di * di);
                d1x = dr * s; d1y = -di * s;
            }
            {
                float pr = wr[io * TOT + 16 + q_], pim = wi[io * TOT + 16 + q_];
                float dr = -pr, di = W1 * (float)p_ - pim;
                float s = 1.0f / (dr * dr + di * di);
                d2x = dr * s; d2y = -di * s;
            }
            float rr = wr[io * TOT + 32 + t];
            float ri = wi[io * TOT + 32 + t];
            __syncthreads();
            Ar[t] = a.x;  Ai[t] = a.y;
            D1r[t] = d1x; D1i[t] = d1y;
            D2r[t] = d2x; D2i[t] = d2y;
            Rr[t] = rr;   Ri[t] = ri;
            __syncthreads();
            float vr = 0.f, vi = 0.f;
#pragma unroll
            for (int f = 0; f < 16; ++f) {
                float ar2 = Ar[f * 16 + q_], ai2 = Ai[f * 16 + q_];
                float dr = D1r[f * 16 + p_], di = D1i[f * 16 + p_];
                vr += ar2 * dr - ai2 * di;
                vi += ar2 * di + ai2 * dr;
            }
            Vr[t] = vr; Vi[t] = vi;
            __syncthreads();
            float tr = 0.f, ti = 0.f;
#pragma unroll
            for (int g = 0; g < 16; ++g) {
                float vr2 = Vr[p_ * 16 + g], vi2 = Vi[p_ * 16 + g];
                float dr = D2r[g * 16 + q_], di = D2i[g * 16 + q_];
                tr += vr2 * dr - vi2 * di;
                ti += vr2 * di + vi2 * dr;
            }
            float rr2 = Rr[t], ri2 = Ri[t];
            accr += rr2 * tr - ri2 * ti;
            acci += rr2 * ti + ri2 * tr;
        }
        or2p[(size_t)ic * 65536 + bo * 256 + t] = make_float2(accr, acci);
    } else {
        // ----- or1[b,o] = sum_i alpha[b,i] * s1[i,o] -----
        int bo = bid - 2048;
        int b = bo >> 5, o = bo & 31;
        float sr = 0.f, si = 0.f;
#pragma unroll 4
        for (int i = 0; i < 32; ++i) {
            float2 a = alpha[(b * 32 + i) * 256 + t];
            float2 s = s1[(i * 32 + o) * 256 + t];
            sr += a.x * s.x - a.y * s.y;
            si += a.x * s.y + a.y * s.x;
        }
        or1[bo * 256 + t] = make_float2(sr, si);
    }
}

// ============ k_x12m: MFMA final stage, term-pair pipelined, or2 reduce folded in.
// Grid 512: o = bid&31, b = (bid>>5)&7, zh = bid>>8. 64 z-rows per block.
__global__ __launch_bounds__(512, 4) void k_x12m(
        const float2* __restrict__ or1v,
        const float2* __restrict__ or2p,
        const u16* __restrict__ e1A,
        const u16* __restrict__ e2B,
        const u16* __restrict__ fA,
        const u16* __restrict__ fB,
        float* __restrict__ out) {
    __shared__ u16 EA[2][2][2048];   // [pairbuf][term-in-pair][64z x 32k]
    __shared__ u16 EB[2][2][4096];   // [pairbuf][term-in-pair][128x x 32k]
    __shared__ u16 GL[2][2048];      // [term-in-pair][64z x 32k]
    __shared__ float2 SM1[256];
    __shared__ float2 SM2[256];

    const int t = threadIdx.x;
    const int l = t & 63, w = t >> 6;
    const int bid = blockIdx.x;
    const int o = bid & 31, b = (bid >> 5) & 7, zh = bid >> 8;
    const int bo = b * 32 + o;
    const int q = l & 15, c4 = l >> 4, k0 = c4 * 8;

    auto stage_pair = [&](int t0, int pb) {
        for (int ch = w; ch < 24; ch += 8) {
            int s = ch >= 12 ? 1 : 0;
            int c = ch - s * 12;
            int tt = t0 + s;
            if (tt > 32) continue;
            const u16* sA;
            const u16* sB;
            if (tt == 0) { sA = fA + zh * 2048; sB = fB; }
            else { int io = (tt - 1) * 32 + o; sA = e1A + io * 4096 + zh * 2048; sB = e2B + io * 4096; }
            const u16* g;
            u16* d;
            if (c < 4) { g = sA + c * 512 + l * 8; d = &EA[pb][s][c * 512]; }
            else { g = sB + (c - 4) * 512 + l * 8; d = &EB[pb][s][(c - 4) * 512]; }
            __builtin_amdgcn_global_load_lds(
                (const __attribute__((address_space(1))) unsigned*)g,
                (__attribute__((address_space(3))) unsigned*)d, 16, 0, 0);
        }
    };

    stage_pair(0, 0);                 // terms 0,1 (issued first: latency overlap)
    if (t < 256) {
        float sr = 0.f, si = 0.f;
#pragma unroll
        for (int ic = 0; ic < 8; ++ic) {
            float2 v = or2p[(size_t)ic * 65536 + bo * 256 + t];
            sr += v.x; si += v.y;
        }
        SM2[t] = make_float2(sr, si);
        SM1[t] = or1v[bo * 256 + t];
    }
    __syncthreads();

    short8 mF0, mF1, mL0, mL1;
#pragma unroll
    for (int j = 0; j < 8; ++j) {
        int k = k0 + j, f = k & 15;
        float2 m1 = SM1[f * 16 + q];
        float2 m2 = SM2[f * 16 + q];
        if (k < 16) {
            mF0[j] = (short)f2bf(m1.x); mF1[j] = (short)f2bf(m1.y);
            mL0[j] = (short)f2bf(m2.x); mL1[j] = (short)f2bf(m2.y);
        } else {
            mF0[j] = (short)f2bf(-m1.y); mF1[j] = (short)f2bf(m1.x);
            mL0[j] = (short)f2bf(-m2.y); mL1[j] = (short)f2bf(m2.x);
        }
    }
    const short8 bF = (w & 1) ? mF1 : mF0;
    const short8 bL = (w & 1) ? mL1 : mL0;

    f32x4 acc[4];
#pragma unroll
    for (int zt = 0; zt < 4; ++zt) acc[zt] = (f32x4){0.f, 0.f, 0.f, 0.f};

    const int zt_g = w >> 1;
    const int zL_g = zt_g * 16 + q;
    const int cw_g = c4 ^ ((zL_g >> 1) & 3);
    const int kk_g = q + ((w & 1) << 4);
    const int x_ = w * 16 + q;
    const int cb_ = c4 ^ ((x_ >> 1) & 3);

    for (int jp = 0; jp < 16; ++jp) {
        int pb = jp & 1;
        int t0 = 2 * jp;
        // --- G phase: both terms of the pair ---
#pragma unroll
        for (int s = 0; s < 2; ++s) {
            short8 aG = *(const short8*)&EA[pb][s][zL_g * 32 + cw_g * 8];
            short8 bG = (t0 + s) ? bL : bF;
            f32x4 g = (f32x4){0.f, 0.f, 0.f, 0.f};
            g = __builtin_amdgcn_mfma_f32_16x16x32_bf16(aG, bG, g, 0, 0, 0);
#pragma unroll
            for (int r = 0; r < 4; ++r) {
                int zz = zt_g * 16 + c4 * 4 + r;
                int cc = (kk_g >> 3) ^ ((zz >> 1) & 3);
                GL[s][zz * 32 + cc * 8 + (kk_g & 7)] = f2bf(g[r]);
            }
        }
        __syncthreads();
        stage_pair(t0 + 2, pb ^ 1);   // prefetch next pair (guards term 33)
        // --- inner phase: both terms ---
#pragma unroll
        for (int s = 0; s < 2; ++s) {
            short8 bf = *(const short8*)&EB[pb][s][x_ * 32 + cb_ * 8];
#pragma unroll
            for (int zt = 0; zt < 4; ++zt) {
                int zL = zt * 16 + q;
                int ca = c4 ^ ((zL >> 1) & 3);
                short8 af = *(const short8*)&GL[s][zL * 32 + ca * 8];
                acc[zt] = __builtin_amdgcn_mfma_f32_16x16x32_bf16(af, bf, acc[zt], 0, 0, 0);
            }
        }
        __syncthreads();
    }
    // --- tail: term 32 (pair slot s=0, pairbuf 0) ---
    {
        short8 aG = *(const short8*)&EA[0][0][zL_g * 32 + cw_g * 8];
        f32x4 g = (f32x4){0.f, 0.f, 0.f, 0.f};
        g = __builtin_amdgcn_mfma_f32_16x16x32_bf16(aG, bL, g, 0, 0, 0);
#pragma unroll
        for (int r = 0; r < 4; ++r) {
            int zz = zt_g * 16 + c4 * 4 + r;
            int cc = (kk_g >> 3) ^ ((zz >> 1) & 3);
            GL[0][zz * 32 + cc * 8 + (kk_g & 7)] = f2bf(g[r]);
        }
        __syncthreads();
        short8 bf = *(const short8*)&EB[0][0][x_ * 32 + cb_ * 8];
#pragma unroll
        for (int zt = 0; zt < 4; ++zt) {
            int zL = zt * 16 + q;
            int ca = c4 ^ ((zL >> 1) & 3);
            short8 af = *(const short8*)&GL[0][zL * 32 + ca * 8];
            acc[zt] = __builtin_amdgcn_mfma_f32_16x16x32_bf16(af, bf, acc[zt], 0, 0, 0);
        }
    }

    const float sc = 1.0f / 16384.0f;
#pragma unroll
    for (int zt = 0; zt < 4; ++zt) {
        int zbase = zh * 64 + zt * 16 + c4 * 4;
        f32x4 a = acc[zt];
#pragma unroll
        for (int r = 0; r < 4; ++r)
            out[(size_t)bo * 16384 + (zbase + r) * 128 + x_] = a[r] * sc;
    }
}

extern "C" void kernel_launch(void* const* d_in, const int* in_sizes, int n_in,
                              void* d_out, int out_size, void* d_ws, size_t ws_size,
                              hipStream_t stream) {
    const float* x  = (const float*)d_in[0];
    const float* wr = (const float*)d_in[1];
    const float* wi = (const float*)d_in[2];
    float* out = (float*)d_out;
    float* ws = (float*)d_ws;

    float2* alpha = (float2*)(ws + 256);
    float2* s1    = (float2*)(ws + 1179904);
    float2* or1   = (float2*)(ws + 1704192);
    u16*    e1A   = (u16*)(ws + 1966336);
    u16*    e2B   = (u16*)(ws + 4063488);
    u16*    fA    = (u16*)(ws + 6160640);
    u16*    fB    = (u16*)(ws + 6162688);
    float2* or2p  = (float2*)(ws + 6164736);

    hipLaunchKernelGGL(k_pre,  dim3(3329), dim3(256), 0, stream,
                       x, wr, wi, e1A, e2B, fA, fB, alpha, s1);
    hipLaunchKernelGGL(k_mid,  dim3(2304), dim3(256), 0, stream,
                       wr, wi, alpha, s1, or1, or2p);
    hipLaunchKernelGGL(k_x12m, dim3(512),  dim3(512), 0, stream,
                       or1, or2p, e1A, e2B, fA, fB, out);
}

// Round 5
// 73.558 us; speedup vs baseline: 5.1328x; 1.5449x over previous
//
#include <hip/hip_runtime.h>

#define TOT 288

typedef short short8 __attribute__((ext_vector_type(8)));
typedef float f32x4 __attribute__((ext_vector_type(4)));
typedef unsigned short u16;
typedef u16 u16x8 __attribute__((ext_vector_type(8)));

__device__ __forceinline__ u16 f2bf(float f) {
    unsigned u = __builtin_bit_cast(unsigned, f);
    u += 0x7fffu + ((u >> 16) & 1u);
    return (u16)(u >> 16);
}

// ---------------- workspace layout (float offsets) ----------------
// alpha  :      256  (131072)       [b][i][f][g] float2
// s1     :  1179904  (524288)       [i][o][f][g] float2
// or1    :  1704192  (131072)       [b][o][f][g] float2
// e1A    :  1966336  (2097152)      bf16 [io][128z][32k] swizzled (A-frag layout)
// e2B    :  4063488  (2097152)      bf16 [io][128x][32k] swizzled (B-frag, k>=16 negated imag)
// fA     :  6160640  (2048)         bf16 Fourier A table
// fB     :  6162688  (2048)         bf16 Fourier B table
// or2p   :  6164736  (1048576)      partial or2 [ic=8][bo=256][pq=256] float2

// ============ k_pre: alpha (0..255) | ebf (256..2303) | tf (2304) | s1 (2305..3328)
// alpha first: it is the longest block type (register-rotation DFT), so it
// starts at t=0 and overlaps the swarm of cheap ebf blocks.
__global__ __launch_bounds__(256) void k_pre(const float* __restrict__ x,
                                             const float* __restrict__ wr,
                                             const float* __restrict__ wi,
                                             u16* __restrict__ e1A, u16* __restrict__ e2B,
                                             u16* __restrict__ fA, u16* __restrict__ fB,
                                             float2* __restrict__ alpha,
                                             float2* __restrict__ s1) {
    __shared__ float sm[4352];
    const int bid = blockIdx.x;
    const int t = threadIdx.x;

    if (bid < 256) {
        // ----- alpha: partial 2D DFT corner, register-rotation twiddles -----
        float* T1r = sm;            // 16 x 132 (padded stride: conflict-free)
        float* T1i = sm + 2112;
        int bi = bid;
        const float* xp = x + (size_t)bi * 16384;
        int xcol = t & 127;
        int f0 = (t >> 7) * 8;
        float ar[8], ai[8], rcr[8], rci[8], str[8], sti[8];
#pragma unroll
        for (int j = 0; j < 8; ++j) {
            ar[j] = 0.f; ai[j] = 0.f;
            rcr[j] = 1.f; rci[j] = 0.f;
            float s, c;
            sincosf(0.049087385212340517f * (float)(f0 + j), &s, &c);
            str[j] = c; sti[j] = -s;
        }
        for (int y = 0; y < 128; ++y) {
            float xv = xp[y * 128 + xcol];
#pragma unroll
            for (int j = 0; j < 8; ++j) {
                ar[j] += rcr[j] * xv;
                ai[j] += rci[j] * xv;
                float nr = rcr[j] * str[j] - rci[j] * sti[j];
                rci[j] = rcr[j] * sti[j] + rci[j] * str[j];
                rcr[j] = nr;
            }
        }
#pragma unroll
        for (int j = 0; j < 8; ++j) {
            T1r[(f0 + j) * 132 + xcol] = ar[j];
            T1i[(f0 + j) * 132 + xcol] = ai[j];
        }
        __syncthreads();

        int g = t & 15, f = t >> 4;
        float sr = 0.f, si = 0.f;
        float c2r = 1.f, c2i = 0.f, s2r, s2i;
        {
            float s, c;
            sincosf(0.049087385212340517f * (float)g, &s, &c);
            s2r = c; s2i = -s;
        }
        for (int xx = 0; xx < 128; ++xx) {
            float trv = T1r[f * 132 + xx], tiv = T1i[f * 132 + xx];
            sr += trv * c2r - tiv * c2i;
            si += trv * c2i + tiv * c2r;
            float nr = c2r * s2r - c2i * s2i;
            c2i = c2r * s2i + c2i * s2r;
            c2r = nr;
        }
        alpha[bi * 256 + t] = make_float2(sr, si);
    } else if (bid < 2304) {
        // ----- ebf: Laplace exponent tables, bf16, frag-swizzled -----
        int idx = bid - 256;
        int io = idx >> 1;
        int mc = (idx & 1) * 256 + t;
        int z = mc >> 2, cp = mc & 3;
        int c = cp ^ ((z >> 1) & 3);
        float tt = (float)z * 0.007874015748031496f;
        u16x8 v1, v2;
#pragma unroll
        for (int j = 0; j < 8; ++j) {
            int k = c * 8 + j, p = k & 15, part = k >> 4;
            {
                float pr = wr[io * TOT + p], pim = wi[io * TOT + p];
                float xx = pr * tt;
                float m = 1.f + xx * (1.f + xx * (0.5f + xx * 0.16666667f));
                float th = pim * tt, th2 = th * th;
                float sn = th * (1.f - th2 * 0.16666667f);
                float cs = 1.f - th2 * 0.5f;
                v1[j] = part ? f2bf(m * sn) : f2bf(m * cs);
            }
            {
                float pr = wr[io * TOT + 16 + p], pim = wi[io * TOT + 16 + p];
                float xx = pr * tt;
                float m = 1.f + xx * (1.f + xx * (0.5f + xx * 0.16666667f));
                float th = pim * tt, th2 = th * th;
                float sn = th * (1.f - th2 * 0.16666667f);
                float cs = 1.f - th2 * 0.5f;
                v2[j] = part ? f2bf(-(m * sn)) : f2bf(m * cs);
            }
        }
        *(u16x8*)(e1A + io * 4096 + mc * 8) = v1;
        *(u16x8*)(e2B + io * 4096 + mc * 8) = v2;
    } else if (bid == 2304) {
        // ----- tf: Fourier bf16 tables -----
        for (int cidx = t; cidx < 1024; cidx += 256) {
            int tbl = cidx >> 9, mc = cidx & 511;
            int z = mc >> 2, cp = mc & 3;
            int c = cp ^ ((z >> 1) & 3);
            u16x8 v;
#pragma unroll
            for (int j = 0; j < 8; ++j) {
                int k = c * 8 + j, f = k & 15, part = k >> 4;
                float th = 0.049087385212340517f * (float)((f * z) & 127);
                float s, cs;
                sincosf(th, &s, &cs);
                float val = part ? ((tbl == 0) ? s : -s) : cs;
                v[j] = f2bf(val);
            }
            u16* dst = (tbl == 0 ? fA : fB) + mc * 8;
            *(u16x8*)dst = v;
        }
    } else {
        // ----- s1 (inline invd): s1[io][f][g] -----
        float* D1r = sm;        float* D1i = sm + 256;
        float* D2r = sm + 512;  float* D2i = sm + 768;
        float* Rr  = sm + 1024; float* Ri  = sm + 1280;
        float* R1r = sm + 1536; float* R1i = sm + 1792;
        int io = bid - 2305;
        const float W1 = 6.2340979026f;
        {
            int p = t & 15, f = t >> 4;
            {
                float pr = wr[io * TOT + p], pim = wi[io * TOT + p];
                float dr = -pr, di = W1 * (float)f - pim;
                float s = 1.0f / (dr * dr + di * di);
                D1r[t] = dr * s; D1i[t] = -di * s;
            }
            {
                float pr = wr[io * TOT + 16 + p], pim = wi[io * TOT + 16 + p];
                float dr = -pr, di = W1 * (float)f - pim;
                float s = 1.0f / (dr * dr + di * di);
                D2r[t] = dr * s; D2i[t] = -di * s;
            }
            Rr[t] = wr[io * TOT + 32 + t];
            Ri[t] = wi[io * TOT + 32 + t];
        }
        __syncthreads();
        int f = t >> 4, q = t & 15;
        float sr = 0.f, si = 0.f;
#pragma unroll
        for (int p = 0; p < 16; ++p) {
            float rr = Rr[p * 16 + q], ri = Ri[p * 16 + q];
            float dr = D1r[f * 16 + p], di = D1i[f * 16 + p];
            sr += rr * dr - ri * di;
            si += rr * di + ri * dr;
        }
        R1r[t] = sr; R1i[t] = si;
        __syncthreads();
        int g = t & 15;
        sr = 0.f; si = 0.f;
#pragma unroll
        for (int qq = 0; qq < 16; ++qq) {
            float rr = R1r[f * 16 + qq], ri = R1i[f * 16 + qq];
            float dr = D2r[g * 16 + qq], di = D2i[g * 16 + qq];
            sr += rr * dr - ri * di;
            si += rr * di + ri * dr;
        }
        s1[io * 256 + f * 16 + g] = make_float2(sr, si);
    }
}

// ============ k_mid: or2p (0..2047) | or1 (2048..2303)
__global__ __launch_bounds__(256) void k_mid(const float* __restrict__ wr,
                                             const float* __restrict__ wi,
                                             const float2* __restrict__ alpha,
                                             const float2* __restrict__ s1,
                                             float2* __restrict__ or1,
                                             float2* __restrict__ or2p) {
    __shared__ float sm[2560];
    const int bid = blockIdx.x;
    const int t = threadIdx.x;

    if (bid < 2048) {
        float* Ar  = sm;        float* Ai  = sm + 256;
        float* D1r = sm + 512;  float* D1i = sm + 768;
        float* D2r = sm + 1024; float* D2i = sm + 1280;
        float* Rr  = sm + 1536; float* Ri  = sm + 1792;
        float* Vr  = sm + 2048; float* Vi  = sm + 2304;
        int bo = bid & 255;
        int ic = bid >> 8;
        int b = bo >> 5, o = bo & 31;
        int p_ = t >> 4, q_ = t & 15;
        const float W1 = 6.2340979026f;
        float accr = 0.f, acci = 0.f;
        for (int ii = 0; ii < 4; ++ii) {
            int i = ic * 4 + ii;
            int io = i * 32 + o;
            float2 a = alpha[(b * 32 + i) * 256 + t];
            float d1x, d1y, d2x, d2y;
            {
                float pr = wr[io * TOT + q_], pim = wi[io * TOT + q_];
                float dr = -pr, di = W1 * (float)p_ - pim;
                float s = 1.0f / (dr * dr + di * di);
                d1x = dr * s; d1y = -di * s;
            }
            {
                float pr = wr[io * TOT + 16 + q_], pim = wi[io * TOT + 16 + q_];
                float dr = -pr, di = W1 * (float)p_ - pim;
                float s = 1.0f / (dr * dr + di * di);
                d2x = dr * s; d2y = -di * s;
            }
            float rr = wr[io * TOT + 32 + t];
            float ri = wi[io * TOT + 32 + t];
            __syncthreads();
            Ar[t] = a.x;  Ai[t] = a.y;
            D1r[t] = d1x; D1i[t] = d1y;
            D2r[t] = d2x; D2i[t] = d2y;
            Rr[t] = rr;   Ri[t] = ri;
            __syncthreads();
            float vr = 0.f, vi = 0.f;
#pragma unroll
            for (int f = 0; f < 16; ++f) {
                float ar2 = Ar[f * 16 + q_], ai2 = Ai[f * 16 + q_];
                float dr = D1r[f * 16 + p_], di = D1i[f * 16 + p_];
                vr += ar2 * dr - ai2 * di;
                vi += ar2 * di + ai2 * dr;
            }
            Vr[t] = vr; Vi[t] = vi;
            __syncthreads();
            float tr = 0.f, ti = 0.f;
#pragma unroll
            for (int g = 0; g < 16; ++g) {
                float vr2 = Vr[p_ * 16 + g], vi2 = Vi[p_ * 16 + g];
                float dr = D2r[g * 16 + q_], di = D2i[g * 16 + q_];
                tr += vr2 * dr - vi2 * di;
                ti += vr2 * di + vi2 * dr;
            }
            float rr2 = Rr[t], ri2 = Ri[t];
            accr += rr2 * tr - ri2 * ti;
            acci += rr2 * ti + ri2 * tr;
        }
        or2p[(size_t)ic * 65536 + bo * 256 + t] = make_float2(accr, acci);
    } else {
        int bo = bid - 2048;
        int b = bo >> 5, o = bo & 31;
        float sr = 0.f, si = 0.f;
#pragma unroll 4
        for (int i = 0; i < 32; ++i) {
            float2 a = alpha[(b * 32 + i) * 256 + t];
            float2 s = s1[(i * 32 + o) * 256 + t];
            sr += a.x * s.x - a.y * s.y;
            si += a.x * s.y + a.y * s.x;
        }
        or1[bo * 256 + t] = make_float2(sr, si);
    }
}

// ============ k_x12m: MFMA final stage, term-pair pipelined, or2 reduce folded in.
__global__ __launch_bounds__(512, 4) void k_x12m(
        const float2* __restrict__ or1v,
        const float2* __restrict__ or2p,
        const u16* __restrict__ e1A,
        const u16* __restrict__ e2B,
        const u16* __restrict__ fA,
        const u16* __restrict__ fB,
        float* __restrict__ out) {
    __shared__ u16 EA[2][2][2048];
    __shared__ u16 EB[2][2][4096];
    __shared__ u16 GL[2][2048];
    __shared__ float2 SM1[256];
    __shared__ float2 SM2[256];

    const int t = threadIdx.x;
    const int l = t & 63, w = t >> 6;
    const int bid = blockIdx.x;
    const int o = bid & 31, b = (bid >> 5) & 7, zh = bid >> 8;
    const int bo = b * 32 + o;
    const int q = l & 15, c4 = l >> 4, k0 = c4 * 8;

    auto stage_pair = [&](int t0, int pb) {
        for (int ch = w; ch < 24; ch += 8) {
            int s = ch >= 12 ? 1 : 0;
            int c = ch - s * 12;
            int tt = t0 + s;
            if (tt > 32) continue;
            const u16* sA;
            const u16* sB;
            if (tt == 0) { sA = fA + zh * 2048; sB = fB; }
            else { int io = (tt - 1) * 32 + o; sA = e1A + io * 4096 + zh * 2048; sB = e2B + io * 4096; }
            const u16* g;
            u16* d;
            if (c < 4) { g = sA + c * 512 + l * 8; d = &EA[pb][s][c * 512]; }
            else { g = sB + (c - 4) * 512 + l * 8; d = &EB[pb][s][(c - 4) * 512]; }
            __builtin_amdgcn_global_load_lds(
                (const __attribute__((address_space(1))) unsigned*)g,
                (__attribute__((address_space(3))) unsigned*)d, 16, 0, 0);
        }
    };

    stage_pair(0, 0);
    if (t < 256) {
        float sr = 0.f, si = 0.f;
#pragma unroll
        for (int ic = 0; ic < 8; ++ic) {
            float2 v = or2p[(size_t)ic * 65536 + bo * 256 + t];
            sr += v.x; si += v.y;
        }
        SM2[t] = make_float2(sr, si);
        SM1[t] = or1v[bo * 256 + t];
    }
    __syncthreads();

    short8 mF0, mF1, mL0, mL1;
#pragma unroll
    for (int j = 0; j < 8; ++j) {
        int k = k0 + j, f = k & 15;
        float2 m1 = SM1[f * 16 + q];
        float2 m2 = SM2[f * 16 + q];
        if (k < 16) {
            mF0[j] = (short)f2bf(m1.x); mF1[j] = (short)f2bf(m1.y);
            mL0[j] = (short)f2bf(m2.x); mL1[j] = (short)f2bf(m2.y);
        } else {
            mF0[j] = (short)f2bf(-m1.y); mF1[j] = (short)f2bf(m1.x);
            mL0[j] = (short)f2bf(-m2.y); mL1[j] = (short)f2bf(m2.x);
        }
    }
    const short8 bF = (w & 1) ? mF1 : mF0;
    const short8 bL = (w & 1) ? mL1 : mL0;

    f32x4 acc[4];
#pragma unroll
    for (int zt = 0; zt < 4; ++zt) acc[zt] = (f32x4){0.f, 0.f, 0.f, 0.f};

    const int zt_g = w >> 1;
    const int zL_g = zt_g * 16 + q;
    const int cw_g = c4 ^ ((zL_g >> 1) & 3);
    const int kk_g = q + ((w & 1) << 4);
    const int x_ = w * 16 + q;
    const int cb_ = c4 ^ ((x_ >> 1) & 3);

    for (int jp = 0; jp < 16; ++jp) {
        int pb = jp & 1;
        int t0 = 2 * jp;
#pragma unroll
        for (int s = 0; s < 2; ++s) {
            short8 aG = *(const short8*)&EA[pb][s][zL_g * 32 + cw_g * 8];
            short8 bG = (t0 + s) ? bL : bF;
            f32x4 g = (f32x4){0.f, 0.f, 0.f, 0.f};
            g = __builtin_amdgcn_mfma_f32_16x16x32_bf16(aG, bG, g, 0, 0, 0);
#pragma unroll
            for (int r = 0; r < 4; ++r) {
                int zz = zt_g * 16 + c4 * 4 + r;
                int cc = (kk_g >> 3) ^ ((zz >> 1) & 3);
                GL[s][zz * 32 + cc * 8 + (kk_g & 7)] = f2bf(g[r]);
            }
        }
        __syncthreads();
        stage_pair(t0 + 2, pb ^ 1);
#pragma unroll
        for (int s = 0; s < 2; ++s) {
            short8 bf = *(const short8*)&EB[pb][s][x_ * 32 + cb_ * 8];
#pragma unroll
            for (int zt = 0; zt < 4; ++zt) {
                int zL = zt * 16 + q;
                int ca = c4 ^ ((zL >> 1) & 3);
                short8 af = *(const short8*)&GL[s][zL * 32 + ca * 8];
                acc[zt] = __builtin_amdgcn_mfma_f32_16x16x32_bf16(af, bf, acc[zt], 0, 0, 0);
            }
        }
        __syncthreads();
    }
    {
        short8 aG = *(const short8*)&EA[0][0][zL_g * 32 + cw_g * 8];
        f32x4 g = (f32x4){0.f, 0.f, 0.f, 0.f};
        g = __builtin_amdgcn_mfma_f32_16x16x32_bf16(aG, bL, g, 0, 0, 0);
#pragma unroll
        for (int r = 0; r < 4; ++r) {
            int zz = zt_g * 16 + c4 * 4 + r;
            int cc = (kk_g >> 3) ^ ((zz >> 1) & 3);
            GL[0][zz * 32 + cc * 8 + (kk_g & 7)] = f2bf(g[r]);
        }
        __syncthreads();
        short8 bf = *(const short8*)&EB[0][0][x_ * 32 + cb_ * 8];
#pragma unroll
        for (int zt = 0; zt < 4; ++zt) {
            int zL = zt * 16 + q;
            int ca = c4 ^ ((zL >> 1) & 3);
            short8 af = *(const short8*)&GL[0][zL * 32 + ca * 8];
            acc[zt] = __builtin_amdgcn_mfma_f32_16x16x32_bf16(af, bf, acc[zt], 0, 0, 0);
        }
    }

    const float sc = 1.0f / 16384.0f;
#pragma unroll
    for (int zt = 0; zt < 4; ++zt) {
        int zbase = zh * 64 + zt * 16 + c4 * 4;
        f32x4 a = acc[zt];
#pragma unroll
        for (int r = 0; r < 4; ++r)
            out[(size_t)bo * 16384 + (zbase + r) * 128 + x_] = a[r] * sc;
    }
}

extern "C" void kernel_launch(void* const* d_in, const int* in_sizes, int n_in,
                              void* d_out, int out_size, void* d_ws, size_t ws_size,
                              hipStream_t stream) {
    const float* x  = (const float*)d_in[0];
    const float* wr = (const float*)d_in[1];
    const float* wi = (const float*)d_in[2];
    float* out = (float*)d_out;
    float* ws = (float*)d_ws;

    float2* alpha = (float2*)(ws + 256);
    float2* s1    = (float2*)(ws + 1179904);
    float2* or1   = (float2*)(ws + 1704192);
    u16*    e1A   = (u16*)(ws + 1966336);
    u16*    e2B   = (u16*)(ws + 4063488);
    u16*    fA    = (u16*)(ws + 6160640);
    u16*    fB    = (u16*)(ws + 6162688);
    float2* or2p  = (float2*)(ws + 6164736);

    hipLaunchKernelGGL(k_pre,  dim3(3329), dim3(256), 0, stream,
                       x, wr, wi, e1A, e2B, fA, fB, alpha, s1);
    hipLaunchKernelGGL(k_mid,  dim3(2304), dim3(256), 0, stream,
                       wr, wi, alpha, s1, or1, or2p);
    hipLaunchKernelGGL(k_x12m, dim3(512),  dim3(512), 0, stream,
                       or1, or2p, e1A, e2B, fA, fB, out);
}

// Round 6
// 55.858 us; speedup vs baseline: 6.7593x; 1.3169x over previous
//
#include <hip/hip_runtime.h>

#define TOT 288

typedef short short8 __attribute__((ext_vector_type(8)));
typedef float f32x4 __attribute__((ext_vector_type(4)));
typedef unsigned short u16;
typedef u16 u16x8 __attribute__((ext_vector_type(8)));

__device__ __forceinline__ u16 f2bf(float f) {
    unsigned u = __builtin_bit_cast(unsigned, f);
    u += 0x7fffu + ((u >> 16) & 1u);
    return (u16)(u >> 16);
}

// ---------------- workspace layout (float offsets) ----------------
// alpha  :      256  (131072)       [b][i][f][g] float2
// s1     :  1179904  (524288)       [i][o][f][g] float2
// or1    :  1704192  (131072)       [b][o][f][g] float2
// S      :  1966336  (262144)       [o][nm=16][pq=256] float2 (Taylor moments, pre-scaled)
// fA     :  6160640  (2048)         bf16 Fourier A table
// fB     :  6162688  (2048)         bf16 Fourier B table
// or2p   :  6164736  (1048576)      partial or2 [ic=8][bo=256][pq=256] float2

// ============ k_pre: alpha (0..255) | s1 (256..1279) | S (1280..1311) | tf (1312)
__global__ __launch_bounds__(256) void k_pre(const float* __restrict__ x,
                                             const float* __restrict__ wr,
                                             const float* __restrict__ wi,
                                             float2* __restrict__ Sv,
                                             u16* __restrict__ fA, u16* __restrict__ fB,
                                             float2* __restrict__ alpha,
                                             float2* __restrict__ s1) {
    __shared__ float sm[4352];
    const int bid = blockIdx.x;
    const int t = threadIdx.x;

    if (bid < 256) {
        // ----- alpha: partial 2D DFT corner, register-rotation twiddles -----
        float* T1r = sm;            // 16 x 132 (padded stride: conflict-free)
        float* T1i = sm + 2112;
        int bi = bid;
        const float* xp = x + (size_t)bi * 16384;
        int xcol = t & 127;
        int f0 = (t >> 7) * 8;
        float ar[8], ai[8], rcr[8], rci[8], str[8], sti[8];
#pragma unroll
        for (int j = 0; j < 8; ++j) {
            ar[j] = 0.f; ai[j] = 0.f;
            rcr[j] = 1.f; rci[j] = 0.f;
            float s, c;
            sincosf(0.049087385212340517f * (float)(f0 + j), &s, &c);
            str[j] = c; sti[j] = -s;
        }
        for (int y = 0; y < 128; ++y) {
            float xv = xp[y * 128 + xcol];
#pragma unroll
            for (int j = 0; j < 8; ++j) {
                ar[j] += rcr[j] * xv;
                ai[j] += rci[j] * xv;
                float nr = rcr[j] * str[j] - rci[j] * sti[j];
                rci[j] = rcr[j] * sti[j] + rci[j] * str[j];
                rcr[j] = nr;
            }
        }
#pragma unroll
        for (int j = 0; j < 8; ++j) {
            T1r[(f0 + j) * 132 + xcol] = ar[j];
            T1i[(f0 + j) * 132 + xcol] = ai[j];
        }
        __syncthreads();

        int g = t & 15, f = t >> 4;
        float sr = 0.f, si = 0.f;
        float c2r = 1.f, c2i = 0.f, s2r, s2i;
        {
            float s, c;
            sincosf(0.049087385212340517f * (float)g, &s, &c);
            s2r = c; s2i = -s;
        }
        for (int xx = 0; xx < 128; ++xx) {
            float trv = T1r[f * 132 + xx], tiv = T1i[f * 132 + xx];
            sr += trv * c2r - tiv * c2i;
            si += trv * c2i + tiv * c2r;
            float nr = c2r * s2r - c2i * s2i;
            c2i = c2r * s2i + c2i * s2r;
            c2r = nr;
        }
        alpha[bi * 256 + t] = make_float2(sr, si);
    } else if (bid < 1280) {
        // ----- s1 (inline invd): s1[io][f][g] -----
        float* D1r = sm;        float* D1i = sm + 256;
        float* D2r = sm + 512;  float* D2i = sm + 768;
        float* Rr  = sm + 1024; float* Ri  = sm + 1280;
        float* R1r = sm + 1536; float* R1i = sm + 1792;
        int io = bid - 256;
        const float W1 = 6.2340979026f;
        {
            int p = t & 15, f = t >> 4;
            {
                float pr = wr[io * TOT + p], pim = wi[io * TOT + p];
                float dr = -pr, di = W1 * (float)f - pim;
                float s = 1.0f / (dr * dr + di * di);
                D1r[t] = dr * s; D1i[t] = -di * s;
            }
            {
                float pr = wr[io * TOT + 16 + p], pim = wi[io * TOT + 16 + p];
                float dr = -pr, di = W1 * (float)f - pim;
                float s = 1.0f / (dr * dr + di * di);
                D2r[t] = dr * s; D2i[t] = -di * s;
            }
            Rr[t] = wr[io * TOT + 32 + t];
            Ri[t] = wi[io * TOT + 32 + t];
        }
        __syncthreads();
        int f = t >> 4, q = t & 15;
        float sr = 0.f, si = 0.f;
#pragma unroll
        for (int p = 0; p < 16; ++p) {
            float rr = Rr[p * 16 + q], ri = Ri[p * 16 + q];
            float dr = D1r[f * 16 + p], di = D1i[f * 16 + p];
            sr += rr * dr - ri * di;
            si += rr * di + ri * dr;
        }
        R1r[t] = sr; R1i[t] = si;
        __syncthreads();
        int g = t & 15;
        sr = 0.f; si = 0.f;
#pragma unroll
        for (int qq = 0; qq < 16; ++qq) {
            float rr = R1r[f * 16 + qq], ri = R1i[f * 16 + qq];
            float dr = D2r[g * 16 + qq], di = D2i[g * 16 + qq];
            sr += rr * dr - ri * di;
            si += rr * di + ri * dr;
        }
        s1[io * 256 + f * 16 + g] = make_float2(sr, si);
    } else if (bid < 1312) {
        // ----- S_o[n,m,p,q] = (1/(n! m! 16384)) sum_i pole1[i,o,p]^n * pole2[i,o,q]^m -----
        int o = bid - 1280;
        int p = t >> 4, q = t & 15;
        float Sr[4][4], Si[4][4];
#pragma unroll
        for (int n = 0; n < 4; ++n)
#pragma unroll
            for (int m = 0; m < 4; ++m) { Sr[n][m] = 0.f; Si[n][m] = 0.f; }
        for (int i = 0; i < 32; ++i) {
            int io = i * 32 + o;
            float p1r = wr[io * TOT + p],      p1i = wi[io * TOT + p];
            float p2r = wr[io * TOT + 16 + q], p2i = wi[io * TOT + 16 + q];
            float a1r[4], a1i[4], a2r[4], a2i[4];
            a1r[0] = 1.f; a1i[0] = 0.f;
            a2r[0] = 1.f; a2i[0] = 0.f;
#pragma unroll
            for (int n = 1; n < 4; ++n) {
                a1r[n] = a1r[n-1] * p1r - a1i[n-1] * p1i;
                a1i[n] = a1r[n-1] * p1i + a1i[n-1] * p1r;
                a2r[n] = a2r[n-1] * p2r - a2i[n-1] * p2i;
                a2i[n] = a2r[n-1] * p2i + a2i[n-1] * p2r;
            }
#pragma unroll
            for (int n = 0; n < 4; ++n)
#pragma unroll
                for (int m = 0; m < 4; ++m) {
                    Sr[n][m] += a1r[n] * a2r[m] - a1i[n] * a2i[m];
                    Si[n][m] += a1r[n] * a2i[m] + a1i[n] * a2r[m];
                }
        }
        const float facs[4] = {1.f, 1.f, 0.5f, 0.16666666666f};
        const float isz = 1.0f / 16384.0f;
#pragma unroll
        for (int n = 0; n < 4; ++n)
#pragma unroll
            for (int m = 0; m < 4; ++m) {
                float fac = facs[n] * facs[m] * isz;
                Sv[(size_t)(o * 16 + n * 4 + m) * 256 + t] =
                    make_float2(Sr[n][m] * fac, Si[n][m] * fac);
            }
    } else {
        // ----- tf: Fourier bf16 tables -----
        for (int cidx = t; cidx < 1024; cidx += 256) {
            int tbl = cidx >> 9, mc = cidx & 511;
            int z = mc >> 2, cp = mc & 3;
            int c = cp ^ ((z >> 1) & 3);
            u16x8 v;
#pragma unroll
            for (int j = 0; j < 8; ++j) {
                int k = c * 8 + j, f = k & 15, part = k >> 4;
                float th = 0.049087385212340517f * (float)((f * z) & 127);
                float s, cs;
                sincosf(th, &s, &cs);
                float val = part ? ((tbl == 0) ? s : -s) : cs;
                v[j] = f2bf(val);
            }
            u16* dst = (tbl == 0 ? fA : fB) + mc * 8;
            *(u16x8*)dst = v;
        }
    }
}

// ============ k_mid: or2p (0..2047) | or1 (2048..2303)
__global__ __launch_bounds__(256) void k_mid(const float* __restrict__ wr,
                                             const float* __restrict__ wi,
                                             const float2* __restrict__ alpha,
                                             const float2* __restrict__ s1,
                                             float2* __restrict__ or1,
                                             float2* __restrict__ or2p) {
    __shared__ float sm[2560];
    const int bid = blockIdx.x;
    const int t = threadIdx.x;

    if (bid < 2048) {
        float* Ar  = sm;        float* Ai  = sm + 256;
        float* D1r = sm + 512;  float* D1i = sm + 768;
        float* D2r = sm + 1024; float* D2i = sm + 1280;
        float* Rr  = sm + 1536; float* Ri  = sm + 1792;
        float* Vr  = sm + 2048; float* Vi  = sm + 2304;
        int bo = bid & 255;
        int ic = bid >> 8;
        int b = bo >> 5, o = bo & 31;
        int p_ = t >> 4, q_ = t & 15;
        const float W1 = 6.2340979026f;
        float accr = 0.f, acci = 0.f;
        for (int ii = 0; ii < 4; ++ii) {
            int i = ic * 4 + ii;
            int io = i * 32 + o;
            float2 a = alpha[(b * 32 + i) * 256 + t];
            float d1x, d1y, d2x, d2y;
            {
                float pr = wr[io * TOT + q_], pim = wi[io * TOT + q_];
                float dr = -pr, di = W1 * (float)p_ - pim;
                float s = 1.0f / (dr * dr + di * di);
                d1x = dr * s; d1y = -di * s;
            }
            {
                float pr = wr[io * TOT + 16 + q_], pim = wi[io * TOT + 16 + q_];
                float dr = -pr, di = W1 * (float)p_ - pim;
                float s = 1.0f / (dr * dr + di * di);
                d2x = dr * s; d2y = -di * s;
            }
            float rr = wr[io * TOT + 32 + t];
            float ri = wi[io * TOT + 32 + t];
            __syncthreads();
            Ar[t] = a.x;  Ai[t] = a.y;
            D1r[t] = d1x; D1i[t] = d1y;
            D2r[t] = d2x; D2i[t] = d2y;
            Rr[t] = rr;   Ri[t] = ri;
            __syncthreads();
            float vr = 0.f, vi = 0.f;
#pragma unroll
            for (int f = 0; f < 16; ++f) {
                float ar2 = Ar[f * 16 + q_], ai2 = Ai[f * 16 + q_];
                float dr = D1r[f * 16 + p_], di = D1i[f * 16 + p_];
                vr += ar2 * dr - ai2 * di;
                vi += ar2 * di + ai2 * dr;
            }
            Vr[t] = vr; Vi[t] = vi;
            __syncthreads();
            float tr = 0.f, ti = 0.f;
#pragma unroll
            for (int g = 0; g < 16; ++g) {
                float vr2 = Vr[p_ * 16 + g], vi2 = Vi[p_ * 16 + g];
                float dr = D2r[g * 16 + q_], di = D2i[g * 16 + q_];
                tr += vr2 * dr - vi2 * di;
                ti += vr2 * di + vi2 * dr;
            }
            float rr2 = Rr[t], ri2 = Ri[t];
            accr += rr2 * tr - ri2 * ti;
            acci += rr2 * ti + ri2 * tr;
        }
        or2p[(size_t)ic * 65536 + bo * 256 + t] = make_float2(accr, acci);
    } else {
        int bo = bid - 2048;
        int b = bo >> 5, o = bo & 31;
        float sr = 0.f, si = 0.f;
#pragma unroll 4
        for (int i = 0; i < 32; ++i) {
            float2 a = alpha[(b * 32 + i) * 256 + t];
            float2 s = s1[(i * 32 + o) * 256 + t];
            sr += a.x * s.x - a.y * s.y;
            si += a.x * s.y + a.y * s.x;
        }
        or1[bo * 256 + t] = make_float2(sr, si);
    }
}

// ============ k_x12m: single Fourier MFMA term + 4x4 Taylor polynomial for x2.
// Grid 512: o = bid&31, b = (bid>>5)&7, zh = bid>>8. 64 z-rows per block.
__global__ __launch_bounds__(512, 4) void k_x12m(
        const float2* __restrict__ or1v,
        const float2* __restrict__ or2p,
        const float2* __restrict__ Sv,
        const u16* __restrict__ fA,
        const u16* __restrict__ fB,
        float* __restrict__ out) {
    __shared__ u16 EA[2048];      // 64 z x 32 k
    __shared__ u16 EB[4096];      // 128 x x 32 k
    __shared__ u16 GL[2048];      // 64 z x 32 k
    __shared__ float2 SM1[256];
    __shared__ float2 SM2[256];
    __shared__ float CP[16];

    const int t = threadIdx.x;
    const int l = t & 63, w = t >> 6;
    const int bid = blockIdx.x;
    const int o = bid & 31, b = (bid >> 5) & 7, zh = bid >> 8;
    const int bo = b * 32 + o;
    const int q = l & 15, c4 = l >> 4, k0 = c4 * 8;

    // stage Fourier tables -> LDS (async)
    for (int ch = w; ch < 12; ch += 8) {
        const u16* g;
        u16* d;
        if (ch < 4) { g = fA + zh * 2048 + ch * 512 + l * 8; d = &EA[ch * 512]; }
        else { g = fB + (ch - 4) * 512 + l * 8; d = &EB[(ch - 4) * 512]; }
        __builtin_amdgcn_global_load_lds(
            (const __attribute__((address_space(1))) unsigned*)g,
            (__attribute__((address_space(3))) unsigned*)d, 16, 0, 0);
    }

    if (t < 256) {
        float sr = 0.f, si = 0.f;
#pragma unroll
        for (int ic = 0; ic < 8; ++ic) {
            float2 v = or2p[(size_t)ic * 65536 + bo * 256 + t];
            sr += v.x; si += v.y;
        }
        SM2[t] = make_float2(sr, si);
        SM1[t] = or1v[bo * 256 + t];
    }
    __syncthreads();   // drains global_load_lds + SM1/SM2 visible

    // ---- Re(c_nm) reduce: group g = t>>5 handles coeff (n,m)=g; lanes j=t&31 ----
    {
        int gidx = t >> 5;
        int j = t & 31;
        const float2* Sg = Sv + (size_t)(o * 16 + gidx) * 256;
        float part = 0.f;
#pragma unroll
        for (int k = 0; k < 8; ++k) {
            int pq = j + 32 * k;
            float2 s = Sg[pq];
            float2 v = SM2[pq];
            part += v.x * s.x - v.y * s.y;
        }
#pragma unroll
        for (int msk = 16; msk >= 1; msk >>= 1)
            part += __shfl_xor(part, msk, 32);
        if (j == 0) CP[gidx] = part;
    }

    // ---- M fragments (Fourier) ----
    short8 mF0, mF1;
#pragma unroll
    for (int j = 0; j < 8; ++j) {
        int k = k0 + j, f = k & 15;
        float2 m1 = SM1[f * 16 + q];
        if (k < 16) { mF0[j] = (short)f2bf(m1.x); mF1[j] = (short)f2bf(m1.y); }
        else        { mF0[j] = (short)f2bf(-m1.y); mF1[j] = (short)f2bf(m1.x); }
    }
    const short8 bF = (w & 1) ? mF1 : mF0;

    const int zt_g = w >> 1;
    const int zL_g = zt_g * 16 + q;
    const int cw_g = c4 ^ ((zL_g >> 1) & 3);
    const int kk_g = q + ((w & 1) << 4);
    const int x_ = w * 16 + q;
    const int cb_ = c4 ^ ((x_ >> 1) & 3);

    // ---- G phase ----
    {
        short8 aG = *(const short8*)&EA[zL_g * 32 + cw_g * 8];
        f32x4 g = (f32x4){0.f, 0.f, 0.f, 0.f};
        g = __builtin_amdgcn_mfma_f32_16x16x32_bf16(aG, bF, g, 0, 0, 0);
#pragma unroll
        for (int r = 0; r < 4; ++r) {
            int zz = zt_g * 16 + c4 * 4 + r;
            int cc = (kk_g >> 3) ^ ((zz >> 1) & 3);
            GL[zz * 32 + cc * 8 + (kk_g & 7)] = f2bf(g[r]);
        }
    }
    __syncthreads();

    // ---- inner phase ----
    f32x4 acc[4];
    {
        short8 bf = *(const short8*)&EB[x_ * 32 + cb_ * 8];
#pragma unroll
        for (int zt = 0; zt < 4; ++zt) {
            int zL = zt * 16 + q;
            int ca = c4 ^ ((zL >> 1) & 3);
            short8 af = *(const short8*)&GL[zL * 32 + ca * 8];
            f32x4 a = (f32x4){0.f, 0.f, 0.f, 0.f};
            acc[zt] = __builtin_amdgcn_mfma_f32_16x16x32_bf16(af, bf, a, 0, 0, 0);
        }
    }

    // ---- epilogue: out = sc*fourier + poly(tz, tx) ----
    const float sc = 1.0f / 16384.0f;
    const float tx = (float)x_ * 0.007874015748031496f;   // x/127
    float R[4];
#pragma unroll
    for (int n = 0; n < 4; ++n)
        R[n] = ((CP[n * 4 + 3] * tx + CP[n * 4 + 2]) * tx + CP[n * 4 + 1]) * tx + CP[n * 4 + 0];
#pragma unroll
    for (int zt = 0; zt < 4; ++zt) {
        int zbase = zh * 64 + zt * 16 + c4 * 4;
        f32x4 a = acc[zt];
#pragma unroll
        for (int r = 0; r < 4; ++r) {
            float tz = (float)(zbase + r) * 0.007874015748031496f;
            float poly = ((R[3] * tz + R[2]) * tz + R[1]) * tz + R[0];
            out[(size_t)bo * 16384 + (zbase + r) * 128 + x_] = a[r] * sc + poly;
        }
    }
}

extern "C" void kernel_launch(void* const* d_in, const int* in_sizes, int n_in,
                              void* d_out, int out_size, void* d_ws, size_t ws_size,
                              hipStream_t stream) {
    const float* x  = (const float*)d_in[0];
    const float* wr = (const float*)d_in[1];
    const float* wi = (const float*)d_in[2];
    float* out = (float*)d_out;
    float* ws = (float*)d_ws;

    float2* alpha = (float2*)(ws + 256);
    float2* s1    = (float2*)(ws + 1179904);
    float2* or1   = (float2*)(ws + 1704192);
    float2* Sv    = (float2*)(ws + 1966336);
    u16*    fA    = (u16*)(ws + 6160640);
    u16*    fB    = (u16*)(ws + 6162688);
    float2* or2p  = (float2*)(ws + 6164736);

    hipLaunchKernelGGL(k_pre,  dim3(1313), dim3(256), 0, stream,
                       x, wr, wi, Sv, fA, fB, alpha, s1);
    hipLaunchKernelGGL(k_mid,  dim3(2304), dim3(256), 0, stream,
                       wr, wi, alpha, s1, or1, or2p);
    hipLaunchKernelGGL(k_x12m, dim3(512),  dim3(512), 0, stream,
                       or1, or2p, Sv, fA, fB, out);
}

// Round 7
// 52.004 us; speedup vs baseline: 7.2603x; 1.0741x over previous
//
#include <hip/hip_runtime.h>

#define TOT 288
#define W1C 6.2340979026f   // 2*pi*127/128

typedef short short8 __attribute__((ext_vector_type(8)));
typedef float f32x4 __attribute__((ext_vector_type(4)));
typedef unsigned short u16;
typedef u16 u16x8 __attribute__((ext_vector_type(8)));

__device__ __forceinline__ u16 f2bf(float f) {
    unsigned u = __builtin_bit_cast(unsigned, f);
    u += 0x7fffu + ((u >> 16) & 1u);
    return (u16)(u >> 16);
}
__device__ __forceinline__ float2 cmul(float2 a, float2 b) {
    return make_float2(a.x * b.x - a.y * b.y, a.x * b.y + a.y * b.x);
}
__device__ __forceinline__ float2 cadd(float2 a, float2 b) {
    return make_float2(a.x + b.x, a.y + b.y);
}
__device__ __forceinline__ float2 cfma(float2 a, float2 b, float2 c) {
    return make_float2(c.x + a.x * b.x - a.y * b.y, c.y + a.x * b.y + a.y * b.x);
}
// chi_j[f]: invd(f,p) = chi_0*( -1/p ) + chi_1*1... basis coeffs over mode index
__device__ __forceinline__ void chi_basis(int f, float2 c[3]) {
    if (f == 0) {
        c[0] = make_float2(1.f, 0.f); c[1] = make_float2(0.f, 0.f); c[2] = make_float2(0.f, 0.f);
    } else {
        float w = W1C * (float)f;
        float iw = 1.0f / w;
        c[0] = make_float2(0.f, 0.f);
        c[1] = make_float2(0.f, -iw);        // 1/(i w)
        c[2] = make_float2(-iw * iw, 0.f);   // 1/(i w)^2
    }
}

// ---------------- workspace layout (float offsets) ----------------
// alpha  :      256  (131072)   [b][i][f][g] float2
// Dv     :  1179904  (18432)    [o][i][jk=9] float2  (res moments)
// or1    :  1704192  (131072)   [b][o][f][g] float2
// S      :  1966336  (262144)   [o][nm=16][pq=256] float2 (Taylor moments)
// fA     :  6160640  (2048)     bf16 Fourier A table
// fB     :  6162688  (2048)     bf16 Fourier B table
// or2p   :  6164736  (1048576)  partial or2 [ic=8][bo=256][pq=256] float2

// ============ k_pre: alpha (0..255) | S (256..287) | D (288..415) | tf (416)
__global__ __launch_bounds__(256) void k_pre(const float* __restrict__ x,
                                             const float* __restrict__ wr,
                                             const float* __restrict__ wi,
                                             float2* __restrict__ Sv,
                                             float2* __restrict__ Dv,
                                             u16* __restrict__ fA, u16* __restrict__ fB,
                                             float2* __restrict__ alpha) {
    __shared__ float sm[4352];
    const int bid = blockIdx.x;
    const int t = threadIdx.x;

    if (bid < 256) {
        // ----- alpha: partial 2D DFT corner, register-rotation twiddles -----
        float* T1r = sm;            // 16 x 132 (padded stride)
        float* T1i = sm + 2112;
        int bi = bid;
        const float* xp = x + (size_t)bi * 16384;
        int xcol = t & 127;
        int f0 = (t >> 7) * 8;
        float ar[8], ai[8], rcr[8], rci[8], str[8], sti[8];
#pragma unroll
        for (int j = 0; j < 8; ++j) {
            ar[j] = 0.f; ai[j] = 0.f;
            rcr[j] = 1.f; rci[j] = 0.f;
            float s, c;
            sincosf(0.049087385212340517f * (float)(f0 + j), &s, &c);
            str[j] = c; sti[j] = -s;
        }
        for (int y = 0; y < 128; ++y) {
            float xv = xp[y * 128 + xcol];
#pragma unroll
            for (int j = 0; j < 8; ++j) {
                ar[j] += rcr[j] * xv;
                ai[j] += rci[j] * xv;
                float nr = rcr[j] * str[j] - rci[j] * sti[j];
                rci[j] = rcr[j] * sti[j] + rci[j] * str[j];
                rcr[j] = nr;
            }
        }
#pragma unroll
        for (int j = 0; j < 8; ++j) {
            T1r[(f0 + j) * 132 + xcol] = ar[j];
            T1i[(f0 + j) * 132 + xcol] = ai[j];
        }
        __syncthreads();

        int g = t & 15, f = t >> 4;
        float sr = 0.f, si = 0.f;
        float c2r = 1.f, c2i = 0.f, s2r, s2i;
        {
            float s, c;
            sincosf(0.049087385212340517f * (float)g, &s, &c);
            s2r = c; s2i = -s;
        }
        for (int xx = 0; xx < 128; ++xx) {
            float trv = T1r[f * 132 + xx], tiv = T1i[f * 132 + xx];
            sr += trv * c2r - tiv * c2i;
            si += trv * c2i + tiv * c2r;
            float nr = c2r * s2r - c2i * s2i;
            c2i = c2r * s2i + c2i * s2r;
            c2r = nr;
        }
        alpha[bi * 256 + t] = make_float2(sr, si);
    } else if (bid < 288) {
        // ----- S_o[n,m,p,q] Taylor moments for x2 polynomial -----
        int o = bid - 256;
        int p = t >> 4, q = t & 15;
        float Sr[4][4], Si[4][4];
#pragma unroll
        for (int n = 0; n < 4; ++n)
#pragma unroll
            for (int m = 0; m < 4; ++m) { Sr[n][m] = 0.f; Si[n][m] = 0.f; }
        for (int i = 0; i < 32; ++i) {
            int io = i * 32 + o;
            float p1r = wr[io * TOT + p],      p1i = wi[io * TOT + p];
            float p2r = wr[io * TOT + 16 + q], p2i = wi[io * TOT + 16 + q];
            float a1r[4], a1i[4], a2r[4], a2i[4];
            a1r[0] = 1.f; a1i[0] = 0.f;
            a2r[0] = 1.f; a2i[0] = 0.f;
#pragma unroll
            for (int n = 1; n < 4; ++n) {
                a1r[n] = a1r[n-1] * p1r - a1i[n-1] * p1i;
                a1i[n] = a1r[n-1] * p1i + a1i[n-1] * p1r;
                a2r[n] = a2r[n-1] * p2r - a2i[n-1] * p2i;
                a2i[n] = a2r[n-1] * p2i + a2i[n-1] * p2r;
            }
#pragma unroll
            for (int n = 0; n < 4; ++n)
#pragma unroll
                for (int m = 0; m < 4; ++m) {
                    Sr[n][m] += a1r[n] * a2r[m] - a1i[n] * a2i[m];
                    Si[n][m] += a1r[n] * a2i[m] + a1i[n] * a2r[m];
                }
        }
        const float facs[4] = {1.f, 1.f, 0.5f, 0.16666666666f};
        const float isz = 1.0f / 16384.0f;
#pragma unroll
        for (int n = 0; n < 4; ++n)
#pragma unroll
            for (int m = 0; m < 4; ++m) {
                float fac = facs[n] * facs[m] * isz;
                Sv[(size_t)(o * 16 + n * 4 + m) * 256 + t] =
                    make_float2(Sr[n][m] * fac, Si[n][m] * fac);
            }
    } else if (bid < 416) {
        // ----- D_jk[i,o] = sum_pq phi_j[p] * R[p,q] * psi_k[q] (res moments) -----
        int base = (bid - 288) * 8;
        int wp = t >> 6, l = t & 63;
#pragma unroll
        for (int s = 0; s < 2; ++s) {
            int io = base + wp * 2 + s;
            float2 Dacc[9];
#pragma unroll
            for (int jk = 0; jk < 9; ++jk) Dacc[jk] = make_float2(0.f, 0.f);
#pragma unroll
            for (int k = 0; k < 4; ++k) {
                int e = l + 64 * k;
                int p = e >> 4, q = e & 15;
                float2 p1 = make_float2(wr[io * TOT + p], wi[io * TOT + p]);
                float i1 = 1.0f / (p1.x * p1.x + p1.y * p1.y);
                float2 phip = make_float2(-p1.x * i1, p1.y * i1);
                float2 p2 = make_float2(wr[io * TOT + 16 + q], wi[io * TOT + 16 + q]);
                float i2 = 1.0f / (p2.x * p2.x + p2.y * p2.y);
                float2 psip = make_float2(-p2.x * i2, p2.y * i2);
                float2 R = make_float2(wr[io * TOT + 32 + e], wi[io * TOT + 32 + e]);
                float2 Rphi[3] = {cmul(R, phip), R, cmul(R, p1)};
                float2 psi[3] = {psip, make_float2(1.f, 0.f), p2};
#pragma unroll
                for (int j = 0; j < 3; ++j)
#pragma unroll
                    for (int k2 = 0; k2 < 3; ++k2)
                        Dacc[j * 3 + k2] = cfma(Rphi[j], psi[k2], Dacc[j * 3 + k2]);
            }
#pragma unroll
            for (int jk = 0; jk < 9; ++jk) {
#pragma unroll
                for (int m = 32; m >= 1; m >>= 1) {
                    Dacc[jk].x += __shfl_xor(Dacc[jk].x, m);
                    Dacc[jk].y += __shfl_xor(Dacc[jk].y, m);
                }
            }
            if (l == 0) {
                int o = io & 31, i = io >> 5;
#pragma unroll
                for (int jk = 0; jk < 9; ++jk)
                    Dv[(size_t)(o * 32 + i) * 9 + jk] = Dacc[jk];
            }
        }
    } else {
        // ----- tf: Fourier bf16 tables -----
        for (int cidx = t; cidx < 1024; cidx += 256) {
            int tbl = cidx >> 9, mc = cidx & 511;
            int z = mc >> 2, cp = mc & 3;
            int c = cp ^ ((z >> 1) & 3);
            u16x8 v;
#pragma unroll
            for (int j = 0; j < 8; ++j) {
                int k = c * 8 + j, f = k & 15, part = k >> 4;
                float th = 0.049087385212340517f * (float)((f * z) & 127);
                float s, cs;
                sincosf(th, &s, &cs);
                float val = part ? ((tbl == 0) ? s : -s) : cs;
                v[j] = f2bf(val);
            }
            u16* dst = (tbl == 0 ? fA : fB) + mc * 8;
            *(u16x8*)dst = v;
        }
    }
}

// ============ k_mid: or1 (0..255) | or2p (256..2303), barrier-light bilinear forms
__global__ __launch_bounds__(256) void k_mid(const float* __restrict__ wr,
                                             const float* __restrict__ wi,
                                             const float2* __restrict__ alpha,
                                             const float2* __restrict__ Dv,
                                             float2* __restrict__ or1,
                                             float2* __restrict__ or2p) {
    __shared__ float2 CaL[4][9];
    const int bid = blockIdx.x;
    const int t = threadIdx.x;

    if (bid < 256) {
        // ----- or1[b,o,f,g] = sum_i alpha[b,i,f,g] * s1_i(f,g),
        //       s1_i = sum_jk D_jk[i,o] * chi_j[f] * xi_k[g] -----
        int bo = bid;
        int b = bo >> 5, o = bo & 31;
        int f = t >> 4, g = t & 15;
        float2 X[3], Xi[3];
        chi_basis(f, X);
        chi_basis(g, Xi);
        float2 B[9];
#pragma unroll
        for (int j = 0; j < 3; ++j)
#pragma unroll
            for (int k = 0; k < 3; ++k)
                B[j * 3 + k] = cmul(X[j], Xi[k]);
        float2 acc = make_float2(0.f, 0.f);
        for (int i = 0; i < 32; ++i) {
            const float2* Dp = Dv + (size_t)(o * 32 + i) * 9;
            float2 s1v = make_float2(0.f, 0.f);
#pragma unroll
            for (int jk = 0; jk < 9; ++jk)
                s1v = cfma(Dp[jk], B[jk], s1v);
            float2 a = alpha[(b * 32 + i) * 256 + t];
            acc = cfma(a, s1v, acc);
        }
        or1[bo * 256 + t] = acc;
    } else {
        // ----- or2 partial: T[p,q] = sum_jk Ca_jk[b,i] phi_j[p] psi_k[q]; acc += R*T -----
        int idx = bid - 256;
        int bo = idx & 255;
        int ic = idx >> 8;
        int b = bo >> 5, o = bo & 31;
        int wp = t >> 6, l = t & 63;
        // prologue: wave wp computes Ca for i = ic*4+wp
        {
            int i = ic * 4 + wp;
            float2 Ca[9];
#pragma unroll
            for (int jk = 0; jk < 9; ++jk) Ca[jk] = make_float2(0.f, 0.f);
#pragma unroll
            for (int k = 0; k < 4; ++k) {
                int e = l + 64 * k;
                int f = e >> 4, g = e & 15;
                float2 X[3], Xi[3];
                chi_basis(f, X);
                chi_basis(g, Xi);
                float2 a = alpha[(b * 32 + i) * 256 + e];
                float2 aX[3] = {cmul(a, X[0]), cmul(a, X[1]), cmul(a, X[2])};
#pragma unroll
                for (int j = 0; j < 3; ++j)
#pragma unroll
                    for (int k2 = 0; k2 < 3; ++k2)
                        Ca[j * 3 + k2] = cfma(aX[j], Xi[k2], Ca[j * 3 + k2]);
            }
#pragma unroll
            for (int jk = 0; jk < 9; ++jk) {
#pragma unroll
                for (int m = 32; m >= 1; m >>= 1) {
                    Ca[jk].x += __shfl_xor(Ca[jk].x, m);
                    Ca[jk].y += __shfl_xor(Ca[jk].y, m);
                }
            }
            if (l == 0) {
#pragma unroll
                for (int jk = 0; jk < 9; ++jk) CaL[wp][jk] = Ca[jk];
            }
        }
        __syncthreads();

        int p_ = t >> 4, q_ = t & 15;
        float2 acc = make_float2(0.f, 0.f);
#pragma unroll
        for (int ii = 0; ii < 4; ++ii) {
            int i = ic * 4 + ii;
            int io = i * 32 + o;
            float2 p1 = make_float2(wr[io * TOT + p_], wi[io * TOT + p_]);
            float i1 = 1.0f / (p1.x * p1.x + p1.y * p1.y);
            float2 phip = make_float2(-p1.x * i1, p1.y * i1);
            float2 p2 = make_float2(wr[io * TOT + 16 + q_], wi[io * TOT + 16 + q_]);
            float i2 = 1.0f / (p2.x * p2.x + p2.y * p2.y);
            float2 psip = make_float2(-p2.x * i2, p2.y * i2);
            float2 R = make_float2(wr[io * TOT + 32 + t], wi[io * TOT + 32 + t]);
            float2 c0 = CaL[ii][0], c1 = CaL[ii][1], c2 = CaL[ii][2];
            float2 c3 = CaL[ii][3], c4 = CaL[ii][4], c5 = CaL[ii][5];
            float2 c6 = CaL[ii][6], c7 = CaL[ii][7], c8 = CaL[ii][8];
            // col_k = Ca[0k]*phip + Ca[1k] + Ca[2k]*p1
            float2 col0 = cfma(c6, p1, cfma(c0, phip, c3));
            float2 col1 = cfma(c7, p1, cfma(c1, phip, c4));
            float2 col2 = cfma(c8, p1, cfma(c2, phip, c5));
            // T = col0*psip + col1 + col2*p2
            float2 T = cfma(col2, p2, cfma(col0, psip, col1));
            acc = cfma(R, T, acc);
        }
        or2p[(size_t)ic * 65536 + bo * 256 + t] = acc;
    }
}

// ============ k_x12m: single Fourier MFMA term + 4x4 Taylor polynomial for x2.
__global__ __launch_bounds__(512, 4) void k_x12m(
        const float2* __restrict__ or1v,
        const float2* __restrict__ or2p,
        const float2* __restrict__ Sv,
        const u16* __restrict__ fA,
        const u16* __restrict__ fB,
        float* __restrict__ out) {
    __shared__ u16 EA[2048];
    __shared__ u16 EB[4096];
    __shared__ u16 GL[2048];
    __shared__ float2 SM1[256];
    __shared__ float2 SM2[256];
    __shared__ float CP[16];

    const int t = threadIdx.x;
    const int l = t & 63, w = t >> 6;
    const int bid = blockIdx.x;
    const int o = bid & 31, b = (bid >> 5) & 7, zh = bid >> 8;
    const int bo = b * 32 + o;
    const int q = l & 15, c4 = l >> 4, k0 = c4 * 8;

    for (int ch = w; ch < 12; ch += 8) {
        const u16* g;
        u16* d;
        if (ch < 4) { g = fA + zh * 2048 + ch * 512 + l * 8; d = &EA[ch * 512]; }
        else { g = fB + (ch - 4) * 512 + l * 8; d = &EB[(ch - 4) * 512]; }
        __builtin_amdgcn_global_load_lds(
            (const __attribute__((address_space(1))) unsigned*)g,
            (__attribute__((address_space(3))) unsigned*)d, 16, 0, 0);
    }

    if (t < 256) {
        float sr = 0.f, si = 0.f;
#pragma unroll
        for (int ic = 0; ic < 8; ++ic) {
            float2 v = or2p[(size_t)ic * 65536 + bo * 256 + t];
            sr += v.x; si += v.y;
        }
        SM2[t] = make_float2(sr, si);
        SM1[t] = or1v[bo * 256 + t];
    }
    __syncthreads();

    {
        int gidx = t >> 5;
        int j = t & 31;
        const float2* Sg = Sv + (size_t)(o * 16 + gidx) * 256;
        float part = 0.f;
#pragma unroll
        for (int k = 0; k < 8; ++k) {
            int pq = j + 32 * k;
            float2 s = Sg[pq];
            float2 v = SM2[pq];
            part += v.x * s.x - v.y * s.y;
        }
#pragma unroll
        for (int msk = 16; msk >= 1; msk >>= 1)
            part += __shfl_xor(part, msk, 32);
        if (j == 0) CP[gidx] = part;
    }

    short8 mF0, mF1;
#pragma unroll
    for (int j = 0; j < 8; ++j) {
        int k = k0 + j, f = k & 15;
        float2 m1 = SM1[f * 16 + q];
        if (k < 16) { mF0[j] = (short)f2bf(m1.x); mF1[j] = (short)f2bf(m1.y); }
        else        { mF0[j] = (short)f2bf(-m1.y); mF1[j] = (short)f2bf(m1.x); }
    }
    const short8 bF = (w & 1) ? mF1 : mF0;

    const int zt_g = w >> 1;
    const int zL_g = zt_g * 16 + q;
    const int cw_g = c4 ^ ((zL_g >> 1) & 3);
    const int kk_g = q + ((w & 1) << 4);
    const int x_ = w * 16 + q;
    const int cb_ = c4 ^ ((x_ >> 1) & 3);

    {
        short8 aG = *(const short8*)&EA[zL_g * 32 + cw_g * 8];
        f32x4 g = (f32x4){0.f, 0.f, 0.f, 0.f};
        g = __builtin_amdgcn_mfma_f32_16x16x32_bf16(aG, bF, g, 0, 0, 0);
#pragma unroll
        for (int r = 0; r < 4; ++r) {
            int zz = zt_g * 16 + c4 * 4 + r;
            int cc = (kk_g >> 3) ^ ((zz >> 1) & 3);
            GL[zz * 32 + cc * 8 + (kk_g & 7)] = f2bf(g[r]);
        }
    }
    __syncthreads();

    f32x4 acc[4];
    {
        short8 bf = *(const short8*)&EB[x_ * 32 + cb_ * 8];
#pragma unroll
        for (int zt = 0; zt < 4; ++zt) {
            int zL = zt * 16 + q;
            int ca = c4 ^ ((zL >> 1) & 3);
            short8 af = *(const short8*)&GL[zL * 32 + ca * 8];
            f32x4 a = (f32x4){0.f, 0.f, 0.f, 0.f};
            acc[zt] = __builtin_amdgcn_mfma_f32_16x16x32_bf16(af, bf, a, 0, 0, 0);
        }
    }

    const float sc = 1.0f / 16384.0f;
    const float tx = (float)x_ * 0.007874015748031496f;
    float R[4];
#pragma unroll
    for (int n = 0; n < 4; ++n)
        R[n] = ((CP[n * 4 + 3] * tx + CP[n * 4 + 2]) * tx + CP[n * 4 + 1]) * tx + CP[n * 4 + 0];
#pragma unroll
    for (int zt = 0; zt < 4; ++zt) {
        int zbase = zh * 64 + zt * 16 + c4 * 4;
        f32x4 a = acc[zt];
#pragma unroll
        for (int r = 0; r < 4; ++r) {
            float tz = (float)(zbase + r) * 0.007874015748031496f;
            float poly = ((R[3] * tz + R[2]) * tz + R[1]) * tz + R[0];
            out[(size_t)bo * 16384 + (zbase + r) * 128 + x_] = a[r] * sc + poly;
        }
    }
}

extern "C" void kernel_launch(void* const* d_in, const int* in_sizes, int n_in,
                              void* d_out, int out_size, void* d_ws, size_t ws_size,
                              hipStream_t stream) {
    const float* x  = (const float*)d_in[0];
    const float* wr = (const float*)d_in[1];
    const float* wi = (const float*)d_in[2];
    float* out = (float*)d_out;
    float* ws = (float*)d_ws;

    float2* alpha = (float2*)(ws + 256);
    float2* Dv    = (float2*)(ws + 1179904);
    float2* or1   = (float2*)(ws + 1704192);
    float2* Sv    = (float2*)(ws + 1966336);
    u16*    fA    = (u16*)(ws + 6160640);
    u16*    fB    = (u16*)(ws + 6162688);
    float2* or2p  = (float2*)(ws + 6164736);

    hipLaunchKernelGGL(k_pre,  dim3(417),  dim3(256), 0, stream,
                       x, wr, wi, Sv, Dv, fA, fB, alpha);
    hipLaunchKernelGGL(k_mid,  dim3(2304), dim3(256), 0, stream,
                       wr, wi, alpha, Dv, or1, or2p);
    hipLaunchKernelGGL(k_x12m, dim3(512),  dim3(512), 0, stream,
                       or1, or2p, Sv, fA, fB, out);
}